// Round 10
// baseline (288.325 us; speedup 1.0000x reference)
//
#include <hip/hip_runtime.h>
#include <hip/hip_bf16.h>
#include <math.h>

#define N_NODES  50000
#define N_EDGES  800000
#define IN_DIM   128
#define HID      256
#define FC1      1024
#define FC2      512
#define N_ACT    16
#define N_AGENTS 8192

#define BM 128
#define BN 128
#define BK 32
#define LDK 40   // padded LDS leading dim for tiled GEMMs

typedef short bf16x8 __attribute__((ext_vector_type(8)));
typedef float floatx4 __attribute__((ext_vector_type(4)));

__device__ __forceinline__ unsigned short f2b(float f) {
    union { float f; unsigned int i; } v;
    v.f = f;
    unsigned int lsb = (v.i >> 16) & 1u;
    v.i += 0x7fffu + lsb;            // round-to-nearest-even
    return (unsigned short)(v.i >> 16);
}

__device__ __forceinline__ float b2f(unsigned short u) {
    union { unsigned int i; float f; } v;
    v.i = ((unsigned int)u) << 16;
    return v.f;
}

__device__ __forceinline__ bf16x8 pack8(float4 a, float4 b) {
    bf16x8 r;
    r[0] = (short)f2b(a.x); r[1] = (short)f2b(a.y);
    r[2] = (short)f2b(a.z); r[3] = (short)f2b(a.w);
    r[4] = (short)f2b(b.x); r[5] = (short)f2b(b.y);
    r[6] = (short)f2b(b.z); r[7] = (short)f2b(b.w);
    return r;
}

// ---- fused: claim marked nodes + in-degree over all edges ----
__global__ __launch_bounds__(256) void prep1_k(const int* __restrict__ agent_idx,
                                               int* __restrict__ nid,
                                               const int* __restrict__ dst,
                                               int* __restrict__ deg) {
    int i = blockIdx.x * 256 + threadIdx.x;
    if (i < N_AGENTS) atomicCAS(&nid[agent_idx[i]], -1, i);
    if (i < N_EDGES) atomicAdd(&deg[dst[i]], 1);
}

// ---- fused: compact ids + bump-alloc row bases + dis = rsqrt(deg+1) ----
__global__ __launch_bounds__(256) void prep2_k(int* __restrict__ nid,
                                               int* __restrict__ list,
                                               int* __restrict__ cnt,
                                               const int* __restrict__ deg,
                                               int* __restrict__ rowbeg,
                                               int* __restrict__ etot,
                                               float* __restrict__ dis) {
    int i = blockIdx.x * 256 + threadIdx.x;
    if (i < N_NODES) {
        int d = deg[i];
        dis[i] = rsqrtf((float)(d + 1));
        if (nid[i] != -1) {
            int c = atomicAdd(cnt, 1);
            nid[i] = c;
            list[c] = i;
            rowbeg[c] = atomicAdd(etot, d);
        }
    }
}

// ---- fill buckets: for needed dsts, append src to its row ----
__global__ __launch_bounds__(256) void fill_k(const int* __restrict__ src,
                                              const int* __restrict__ dst,
                                              const int* __restrict__ nid,
                                              const int* __restrict__ rowbeg,
                                              int* __restrict__ fill,
                                              int* __restrict__ ebuf) {
    int e = blockIdx.x * 256 + threadIdx.x;
    if (e >= N_EDGES) return;
    int c = nid[dst[e]];
    if (c < 0) return;
    int p = atomicAdd(&fill[c], 1);
    ebuf[rowbeg[c] + p] = src[e];
}

// ---- weight transpose+convert via LDS tiles: f32 [K,N] -> bf16 [N,K] ----
// 64x64 tiles; coalesced f32 reads AND coalesced 16B bf16 writes. (Wmu stays f32.)
__global__ __launch_bounds__(256) void wtr_k(const float* __restrict__ Wgcn,
                                             const float* __restrict__ W1,
                                             const float* __restrict__ W2,
                                             unsigned short* __restrict__ wgcn_t,
                                             unsigned short* __restrict__ w1_t,
                                             unsigned short* __restrict__ w2_t) {
    __shared__ unsigned short Ts[64][72];
    int b = blockIdx.x;
    const float* src; unsigned short* dst; int K, N, tk, tn;
    if (b < 8)        { src = Wgcn; dst = wgcn_t; K = IN_DIM; N = HID;  tk = b >> 2;        tn = b & 3; }
    else if (b < 72)  { int bb = b - 8;  src = W1; dst = w1_t; K = HID;  N = FC1;  tk = bb >> 4; tn = bb & 15; }
    else              { int bb = b - 72; src = W2; dst = w2_t; K = FC1;  N = FC2;  tk = bb >> 3; tn = bb & 7; }
    int k0 = tk * 64, n0 = tn * 64;
    int tid = threadIdx.x;
    int r  = tid >> 2;
    int cc = (tid & 3) * 16;
    {
        const float* p = src + (size_t)(k0 + r) * N + n0 + cc;
        #pragma unroll
        for (int i = 0; i < 16; i += 4) {
            float4 v = *(const float4*)(p + i);
            Ts[r][cc + i + 0] = f2b(v.x);
            Ts[r][cc + i + 1] = f2b(v.y);
            Ts[r][cc + i + 2] = f2b(v.z);
            Ts[r][cc + i + 3] = f2b(v.w);
        }
    }
    __syncthreads();
    int n = tid >> 2;
    {
        bf16x8 o0, o1;
        #pragma unroll
        for (int i = 0; i < 8; ++i) o0[i] = (short)Ts[cc + i][n];
        #pragma unroll
        for (int i = 0; i < 8; ++i) o1[i] = (short)Ts[cc + 8 + i][n];
        unsigned short* q = dst + (size_t)(n0 + n) * K + k0 + cc;
        *(bf16x8*)q = o0;
        *(bf16x8*)(q + 8) = o1;
    }
}

// ---- accumulate per needed node: sum in-edges + self-loop + bias, relu -> bf16 ----
__global__ __launch_bounds__(256) void accum_k(const int* __restrict__ cntp,
                                               const int* __restrict__ list,
                                               const int* __restrict__ rowbeg,
                                               const int* __restrict__ deg,
                                               const int* __restrict__ ebuf,
                                               const float* __restrict__ dis,
                                               const unsigned short* __restrict__ xw,
                                               const float* __restrict__ bgcn,
                                               unsigned short* __restrict__ h_node) {
    int c = blockIdx.x;
    if (c >= *cntp) return;
    int n = list[c];
    int lane = threadIdx.x & 63;
    int wave = threadIdx.x >> 6;
    int beg = rowbeg[c];
    int end = beg + deg[n];
    float dn = dis[n];
    floatx4 acc = {0.0f, 0.0f, 0.0f, 0.0f};
    for (int i = beg + wave; i < end; i += 4) {
        int s = ebuf[i];
        float w = dis[s] * dn;
        ushort4 u = *(const ushort4*)(xw + (size_t)s * HID + lane * 4);
        acc.x += w * b2f(u.x);
        acc.y += w * b2f(u.y);
        acc.z += w * b2f(u.z);
        acc.w += w * b2f(u.w);
    }
    __shared__ float part[4][HID];
    part[wave][lane * 4 + 0] = acc.x;
    part[wave][lane * 4 + 1] = acc.y;
    part[wave][lane * 4 + 2] = acc.z;
    part[wave][lane * 4 + 3] = acc.w;
    __syncthreads();
    int t = threadIdx.x;
    float v = part[0][t] + part[1][t] + part[2][t] + part[3][t];
    v += b2f(xw[(size_t)n * HID + t]) * dn * dn + bgcn[t];
    if (v < 0.0f) v = 0.0f;
    h_node[(size_t)c * HID + t] = f2b(v);
}

// ---- tiled GEMM (bf16 A): C = A @ Bt^T, bf16(v + bias) out ----
__global__ __launch_bounds__(256) void gemm_tiled_k(const unsigned short* __restrict__ A,
                                                    const unsigned short* __restrict__ Bt,
                                                    const float* __restrict__ bias,
                                                    unsigned short* __restrict__ outb,
                                                    int M, int N, int K) {
    __shared__ unsigned short As[BM][LDK];
    __shared__ unsigned short Bs[BN][LDK];

    int tn = blockIdx.x;
    int tm = blockIdx.y;
    int tid = threadIdx.x;
    int lane = tid & 63;
    int wave = tid >> 6;
    int wm = wave >> 1, wn = wave & 1;
    int r16 = lane & 15, quad = lane >> 4;

    int srow = tid >> 2;
    int scol = (tid & 3) * 8;
    const unsigned short* pa0 = A + (size_t)(tm * BM + srow) * K + scol;
    const unsigned short* pa1 = A + (size_t)(tm * BM + srow + 64) * K + scol;
    const unsigned short* pb0 = Bt + (size_t)(tn * BN + srow) * K + scol;
    const unsigned short* pb1 = Bt + (size_t)(tn * BN + srow + 64) * K + scol;

    floatx4 acc[4][4];
    #pragma unroll
    for (int i = 0; i < 4; ++i)
        #pragma unroll
        for (int j = 0; j < 4; ++j)
            acc[i][j] = (floatx4){0.0f, 0.0f, 0.0f, 0.0f};

    bf16x8 ra0 = *(const bf16x8*)pa0;
    bf16x8 ra1 = *(const bf16x8*)pa1;
    bf16x8 rb0 = *(const bf16x8*)pb0;
    bf16x8 rb1 = *(const bf16x8*)pb1;

    for (int k0 = 0; k0 < K; k0 += BK) {
        *(bf16x8*)&As[srow][scol]      = ra0;
        *(bf16x8*)&As[srow + 64][scol] = ra1;
        *(bf16x8*)&Bs[srow][scol]      = rb0;
        *(bf16x8*)&Bs[srow + 64][scol] = rb1;
        __syncthreads();

        if (k0 + BK < K) {
            ra0 = *(const bf16x8*)(pa0 + k0 + BK);
            ra1 = *(const bf16x8*)(pa1 + k0 + BK);
            rb0 = *(const bf16x8*)(pb0 + k0 + BK);
            rb1 = *(const bf16x8*)(pb1 + k0 + BK);
        }

        bf16x8 af[4], bfr[4];
        #pragma unroll
        for (int i = 0; i < 4; ++i)
            af[i] = *(const bf16x8*)&As[wm * 64 + i * 16 + r16][quad * 8];
        #pragma unroll
        for (int j = 0; j < 4; ++j)
            bfr[j] = *(const bf16x8*)&Bs[wn * 64 + j * 16 + r16][quad * 8];
        #pragma unroll
        for (int i = 0; i < 4; ++i)
            #pragma unroll
            for (int j = 0; j < 4; ++j)
                acc[i][j] = __builtin_amdgcn_mfma_f32_16x16x32_bf16(af[i], bfr[j], acc[i][j], 0, 0, 0);
        __syncthreads();
    }

    #pragma unroll
    for (int j = 0; j < 4; ++j) {
        int ocol = tn * BN + wn * 64 + j * 16 + r16;
        float bv = bias[ocol];
        #pragma unroll
        for (int i = 0; i < 4; ++i) {
            int orow = tm * BM + wm * 64 + i * 16 + quad * 4;
            #pragma unroll
            for (int r = 0; r < 4; ++r)
                outb[(size_t)(orow + r) * N + ocol] = f2b(acc[i][j][r] + bv);
        }
    }
}

// ---- tiled GEMM, A rows gathered indirectly (FC1 + agent gather fused) ----
// zb[a,:] = h_node[nid[agent[a]]] @ w1t^T + b1   (row map is K-invariant)
__global__ __launch_bounds__(256) void gemm_tiled_gather_k(const unsigned short* __restrict__ h_node,
                                                           const int* __restrict__ agent,
                                                           const int* __restrict__ nid,
                                                           const unsigned short* __restrict__ Bt,
                                                           const float* __restrict__ bias,
                                                           unsigned short* __restrict__ outb,
                                                           int M, int N, int K) {
    __shared__ unsigned short As[BM][LDK];
    __shared__ unsigned short Bs[BN][LDK];

    int tn = blockIdx.x;
    int tm = blockIdx.y;
    int tid = threadIdx.x;
    int lane = tid & 63;
    int wave = tid >> 6;
    int wm = wave >> 1, wn = wave & 1;
    int r16 = lane & 15, quad = lane >> 4;

    int srow = tid >> 2;
    int scol = (tid & 3) * 8;
    int c0 = nid[agent[tm * BM + srow]];
    int c1 = nid[agent[tm * BM + srow + 64]];
    const unsigned short* pa0 = h_node + (size_t)c0 * K + scol;
    const unsigned short* pa1 = h_node + (size_t)c1 * K + scol;
    const unsigned short* pb0 = Bt + (size_t)(tn * BN + srow) * K + scol;
    const unsigned short* pb1 = Bt + (size_t)(tn * BN + srow + 64) * K + scol;

    floatx4 acc[4][4];
    #pragma unroll
    for (int i = 0; i < 4; ++i)
        #pragma unroll
        for (int j = 0; j < 4; ++j)
            acc[i][j] = (floatx4){0.0f, 0.0f, 0.0f, 0.0f};

    bf16x8 ra0 = *(const bf16x8*)pa0;
    bf16x8 ra1 = *(const bf16x8*)pa1;
    bf16x8 rb0 = *(const bf16x8*)pb0;
    bf16x8 rb1 = *(const bf16x8*)pb1;

    for (int k0 = 0; k0 < K; k0 += BK) {
        *(bf16x8*)&As[srow][scol]      = ra0;
        *(bf16x8*)&As[srow + 64][scol] = ra1;
        *(bf16x8*)&Bs[srow][scol]      = rb0;
        *(bf16x8*)&Bs[srow + 64][scol] = rb1;
        __syncthreads();

        if (k0 + BK < K) {
            ra0 = *(const bf16x8*)(pa0 + k0 + BK);
            ra1 = *(const bf16x8*)(pa1 + k0 + BK);
            rb0 = *(const bf16x8*)(pb0 + k0 + BK);
            rb1 = *(const bf16x8*)(pb1 + k0 + BK);
        }

        bf16x8 af[4], bfr[4];
        #pragma unroll
        for (int i = 0; i < 4; ++i)
            af[i] = *(const bf16x8*)&As[wm * 64 + i * 16 + r16][quad * 8];
        #pragma unroll
        for (int j = 0; j < 4; ++j)
            bfr[j] = *(const bf16x8*)&Bs[wn * 64 + j * 16 + r16][quad * 8];
        #pragma unroll
        for (int i = 0; i < 4; ++i)
            #pragma unroll
            for (int j = 0; j < 4; ++j)
                acc[i][j] = __builtin_amdgcn_mfma_f32_16x16x32_bf16(af[i], bfr[j], acc[i][j], 0, 0, 0);
        __syncthreads();
    }

    #pragma unroll
    for (int j = 0; j < 4; ++j) {
        int ocol = tn * BN + wn * 64 + j * 16 + r16;
        float bv = bias[ocol];
        #pragma unroll
        for (int i = 0; i < 4; ++i) {
            int orow = tm * BM + wm * 64 + i * 16 + quad * 4;
            #pragma unroll
            for (int r = 0; r < 4; ++r)
                outb[(size_t)(orow + r) * N + ocol] = f2b(acc[i][j][r] + bv);
        }
    }
}

// ---- tiled GEMM with f32 A (converts during LDS staging): xw = x @ Wgcn ----
__global__ __launch_bounds__(256) void gemm_tiled_f32a_k(const float* __restrict__ A,
                                                         const unsigned short* __restrict__ Bt,
                                                         unsigned short* __restrict__ outb,
                                                         int M, int N, int K) {
    __shared__ unsigned short As[BM][LDK];
    __shared__ unsigned short Bs[BN][LDK];

    int tn = blockIdx.x;
    int tm = blockIdx.y;
    int tid = threadIdx.x;
    int lane = tid & 63;
    int wave = tid >> 6;
    int wm = wave >> 1, wn = wave & 1;
    int r16 = lane & 15, quad = lane >> 4;

    int srow = tid >> 2;
    int scol = (tid & 3) * 8;
    int ar0 = tm * BM + srow;        if (ar0 > M - 1) ar0 = M - 1;
    int ar1 = tm * BM + srow + 64;   if (ar1 > M - 1) ar1 = M - 1;
    const float* pa0 = A + (size_t)ar0 * K + scol;
    const float* pa1 = A + (size_t)ar1 * K + scol;
    const unsigned short* pb0 = Bt + (size_t)(tn * BN + srow) * K + scol;
    const unsigned short* pb1 = Bt + (size_t)(tn * BN + srow + 64) * K + scol;

    floatx4 acc[4][4];
    #pragma unroll
    for (int i = 0; i < 4; ++i)
        #pragma unroll
        for (int j = 0; j < 4; ++j)
            acc[i][j] = (floatx4){0.0f, 0.0f, 0.0f, 0.0f};

    float4 ra0a = *(const float4*)pa0, ra0b = *(const float4*)(pa0 + 4);
    float4 ra1a = *(const float4*)pa1, ra1b = *(const float4*)(pa1 + 4);
    bf16x8 rb0 = *(const bf16x8*)pb0;
    bf16x8 rb1 = *(const bf16x8*)pb1;

    for (int k0 = 0; k0 < K; k0 += BK) {
        *(bf16x8*)&As[srow][scol]      = pack8(ra0a, ra0b);
        *(bf16x8*)&As[srow + 64][scol] = pack8(ra1a, ra1b);
        *(bf16x8*)&Bs[srow][scol]      = rb0;
        *(bf16x8*)&Bs[srow + 64][scol] = rb1;
        __syncthreads();

        if (k0 + BK < K) {
            ra0a = *(const float4*)(pa0 + k0 + BK);
            ra0b = *(const float4*)(pa0 + k0 + BK + 4);
            ra1a = *(const float4*)(pa1 + k0 + BK);
            ra1b = *(const float4*)(pa1 + k0 + BK + 4);
            rb0 = *(const bf16x8*)(pb0 + k0 + BK);
            rb1 = *(const bf16x8*)(pb1 + k0 + BK);
        }

        bf16x8 af[4], bfr[4];
        #pragma unroll
        for (int i = 0; i < 4; ++i)
            af[i] = *(const bf16x8*)&As[wm * 64 + i * 16 + r16][quad * 8];
        #pragma unroll
        for (int j = 0; j < 4; ++j)
            bfr[j] = *(const bf16x8*)&Bs[wn * 64 + j * 16 + r16][quad * 8];
        #pragma unroll
        for (int i = 0; i < 4; ++i)
            #pragma unroll
            for (int j = 0; j < 4; ++j)
                acc[i][j] = __builtin_amdgcn_mfma_f32_16x16x32_bf16(af[i], bfr[j], acc[i][j], 0, 0, 0);
        __syncthreads();
    }

    #pragma unroll
    for (int j = 0; j < 4; ++j) {
        int ocol = tn * BN + wn * 64 + j * 16 + r16;
        #pragma unroll
        for (int i = 0; i < 4; ++i) {
            int orow_base = tm * BM + wm * 64 + i * 16 + quad * 4;
            #pragma unroll
            for (int r = 0; r < 4; ++r) {
                int orow = orow_base + r;
                if (orow < M)
                    outb[(size_t)orow * N + ocol] = f2b(acc[i][j][r]);
            }
        }
    }
}

// ---- single-pass row LayerNorm (+affine) + relu, bf16 in -> bf16 out (FC1) ----
__global__ __launch_bounds__(256) void ln_relu_k(const unsigned short* __restrict__ z,
                                                 const float* __restrict__ g,
                                                 const float* __restrict__ be,
                                                 unsigned short* __restrict__ out, int L) {
    size_t base = (size_t)blockIdx.x * L;
    int nc = L >> 8;
    float vreg[4];
    float s = 0.0f, s2 = 0.0f;
    for (int i = 0; i < nc; ++i) {
        float v = b2f(z[base + i * 256 + threadIdx.x]);
        vreg[i] = v;
        s += v;
        s2 += v * v;
    }
    for (int off = 32; off > 0; off >>= 1) {
        s += __shfl_down(s, off);
        s2 += __shfl_down(s2, off);
    }
    __shared__ float red[8];
    int wave = threadIdx.x >> 6;
    int lane = threadIdx.x & 63;
    if (lane == 0) { red[wave] = s; red[4 + wave] = s2; }
    __syncthreads();
    s  = red[0] + red[1] + red[2] + red[3];
    s2 = red[4] + red[5] + red[6] + red[7];
    float invL = 1.0f / (float)L;
    float mean = s * invL;
    float var = s2 * invL - mean * mean;
    float inv = rsqrtf(var + 1e-5f);
    for (int i = 0; i < nc; ++i) {
        int c = i * 256 + threadIdx.x;
        float v = (vreg[i] - mean) * inv * g[c] + be[c];
        if (v < 0.0f) v = 0.0f;
        out[base + c] = f2b(v);
    }
}

// ---- fused LN2 + ReLU + head: out = sigmoid(relu(LN(z)*g+be) @ Wmu + bmu) ----
// One block per agent row; h2 never exists. Wmu read as raw f32 [FC2][N_ACT]
// (64 B/thread, perfectly coalesced, L2-resident).
__global__ __launch_bounds__(256) void ln2_head_k(const unsigned short* __restrict__ z,
                                                  const float* __restrict__ g2,
                                                  const float* __restrict__ be2,
                                                  const float* __restrict__ Wmu,
                                                  const float* __restrict__ bmu,
                                                  float* __restrict__ out) {
    size_t base = (size_t)blockIdx.x * FC2;
    int tid = threadIdx.x;
    int wave = tid >> 6, lane = tid & 63;
    float v0 = b2f(z[base + tid]);
    float v1 = b2f(z[base + 256 + tid]);
    float s = v0 + v1, s2 = v0 * v0 + v1 * v1;
    for (int off = 32; off > 0; off >>= 1) {
        s += __shfl_down(s, off);
        s2 += __shfl_down(s2, off);
    }
    __shared__ float red[8];
    if (lane == 0) { red[wave] = s; red[4 + wave] = s2; }
    __syncthreads();
    s  = red[0] + red[1] + red[2] + red[3];
    s2 = red[4] + red[5] + red[6] + red[7];
    float mean = s * (1.0f / FC2);
    float var = s2 * (1.0f / FC2) - mean * mean;
    float inv = rsqrtf(var + 1e-5f);
    v0 = (v0 - mean) * inv * g2[tid] + be2[tid];
    v1 = (v1 - mean) * inv * g2[256 + tid] + be2[256 + tid];
    if (v0 < 0.0f) v0 = 0.0f;
    if (v1 < 0.0f) v1 = 0.0f;
    // head partials: p[o] = v0*Wmu[tid][o] + v1*Wmu[tid+256][o]
    const float4* w0 = (const float4*)(Wmu + (size_t)tid * N_ACT);
    const float4* w1 = (const float4*)(Wmu + (size_t)(tid + 256) * N_ACT);
    float p[N_ACT];
    #pragma unroll
    for (int q = 0; q < 4; ++q) {
        float4 a = w0[q], b = w1[q];
        p[q * 4 + 0] = v0 * a.x + v1 * b.x;
        p[q * 4 + 1] = v0 * a.y + v1 * b.y;
        p[q * 4 + 2] = v0 * a.z + v1 * b.z;
        p[q * 4 + 3] = v0 * a.w + v1 * b.w;
    }
    __shared__ float hp[4][N_ACT];
    #pragma unroll
    for (int o = 0; o < N_ACT; ++o) {
        float pv = p[o];
        for (int off = 32; off > 0; off >>= 1) pv += __shfl_down(pv, off);
        if (lane == 0) hp[wave][o] = pv;
    }
    __syncthreads();
    if (tid < N_ACT) {
        float v = hp[0][tid] + hp[1][tid] + hp[2][tid] + hp[3][tid] + bmu[tid];
        v = 1.0f / (1.0f + expf(-v));
        out[(size_t)blockIdx.x * N_ACT + tid] = v;
    }
}

extern "C" void kernel_launch(void* const* d_in, const int* in_sizes, int n_in,
                              void* d_out, int out_size, void* d_ws, size_t ws_size,
                              hipStream_t stream) {
    const float* x    = (const float*)d_in[0];
    const int*   ei   = (const int*)d_in[1];
    const int*   agent= (const int*)d_in[2];
    const float* Wgcn = (const float*)d_in[3];
    const float* bgcn = (const float*)d_in[4];
    const float* W1   = (const float*)d_in[5];
    const float* b1   = (const float*)d_in[6];
    const float* g1   = (const float*)d_in[7];
    const float* be1  = (const float*)d_in[8];
    const float* W2   = (const float*)d_in[9];
    const float* b2   = (const float*)d_in[10];
    const float* g2   = (const float*)d_in[11];
    const float* be2  = (const float*)d_in[12];
    const float* Wmu  = (const float*)d_in[13];
    const float* bmu  = (const float*)d_in[14];
    float* out = (float*)d_out;

    const int* srcp = ei;
    const int* dstp = ei + N_EDGES;

    // workspace layout (256B aligned). Zero-init region is contiguous: deg|fill|cnt|etot.
    char* ws = (char*)d_ws;
    size_t off = 0;
    char* zero_base = ws;
    int* deg = (int*)(ws + off);     off += ((size_t)N_NODES * 4 + 255) & ~(size_t)255;
    int* fill = (int*)(ws + off);    off += ((size_t)N_AGENTS * 4 + 255) & ~(size_t)255;
    int* cnt = (int*)(ws + off);     off += 256;
    int* etot = (int*)(ws + off);    off += 256;
    size_t zero_bytes = off;
    int* nid = (int*)(ws + off);     off += ((size_t)N_NODES * 4 + 255) & ~(size_t)255;
    float* dis = (float*)(ws + off); off += ((size_t)N_NODES * 4 + 255) & ~(size_t)255;
    int* list = (int*)(ws + off);    off += ((size_t)N_AGENTS * 4 + 255) & ~(size_t)255;
    int* rowbeg = (int*)(ws + off);  off += ((size_t)N_AGENTS * 4 + 255) & ~(size_t)255;
    int* ebuf = (int*)(ws + off);    off += ((size_t)N_EDGES * 4 + 255) & ~(size_t)255;
    unsigned short* wgcn_t = (unsigned short*)(ws + off); off += ((size_t)IN_DIM * HID * 2 + 255) & ~(size_t)255;
    unsigned short* w1_t   = (unsigned short*)(ws + off); off += ((size_t)HID * FC1 * 2 + 255) & ~(size_t)255;
    unsigned short* w2_t   = (unsigned short*)(ws + off); off += ((size_t)FC1 * FC2 * 2 + 255) & ~(size_t)255;
    unsigned short* xw     = (unsigned short*)(ws + off); off += ((size_t)N_NODES * HID * 2 + 255) & ~(size_t)255;
    unsigned short* h_node = (unsigned short*)(ws + off); off += ((size_t)N_AGENTS * HID * 2 + 255) & ~(size_t)255;
    unsigned short* zb = (unsigned short*)(ws + off);     off += ((size_t)N_AGENTS * FC1 * 2 + 255) & ~(size_t)255;
    unsigned short* h1 = (unsigned short*)(ws + off);     off += ((size_t)N_AGENTS * FC1 * 2 + 255) & ~(size_t)255;

    // ---- init via memset (replaces init_k): zeros + nid=-1 (0xFF per byte) ----
    hipMemsetAsync(zero_base, 0, zero_bytes, stream);
    hipMemsetAsync(nid, 0xFF, (size_t)N_NODES * 4, stream);

    // ---- graph prep / CSR build ----
    prep1_k<<<(N_EDGES + 255) / 256, 256, 0, stream>>>(agent, nid, dstp, deg);
    prep2_k<<<(N_NODES + 255) / 256, 256, 0, stream>>>(nid, list, cnt, deg, rowbeg, etot, dis);
    fill_k<<<(N_EDGES + 255) / 256, 256, 0, stream>>>(srcp, dstp, nid, rowbeg, fill, ebuf);

    // ---- weight transpose+convert (Wgcn, W1, W2; Wmu used raw f32) ----
    wtr_k<<<200, 256, 0, stream>>>(Wgcn, W1, W2, wgcn_t, w1_t, w2_t);

    // xw = x @ W_gcn (f32 A converted during staging)
    {
        dim3 grid(HID / BN, (N_NODES + BM - 1) / BM);
        gemm_tiled_f32a_k<<<grid, 256, 0, stream>>>(x, wgcn_t, xw, N_NODES, HID, IN_DIM);
    }

    // per-needed-node aggregation
    accum_k<<<N_AGENTS, 256, 0, stream>>>(cnt, list, rowbeg, deg, ebuf, dis, xw, bgcn, h_node);

    // FC1 (agent gather fused into A staging) -> LN+relu
    {
        dim3 grid(FC1 / BN, N_AGENTS / BM);
        gemm_tiled_gather_k<<<grid, 256, 0, stream>>>(h_node, agent, nid, w1_t, b1, zb,
                                                      N_AGENTS, FC1, HID);
        ln_relu_k<<<N_AGENTS, 256, 0, stream>>>(zb, g1, be1, h1, FC1);
    }

    // FC2 -> fused LN + head
    {
        dim3 grid(FC2 / BN, N_AGENTS / BM);
        gemm_tiled_k<<<grid, 256, 0, stream>>>(h1, w2_t, b2, zb, N_AGENTS, FC2, FC1);
        ln2_head_k<<<N_AGENTS, 256, 0, stream>>>(zb, g2, be2, Wmu, bmu, out);
    }
}

// Round 11
// 254.219 us; speedup vs baseline: 1.1342x; 1.1342x over previous
//
#include <hip/hip_runtime.h>
#include <hip/hip_bf16.h>
#include <math.h>

#define N_NODES  50000
#define N_EDGES  800000
#define IN_DIM   128
#define HID      256
#define FC1      1024
#define FC2      512
#define N_ACT    16
#define N_AGENTS 8192

#define BM 128
#define BN 128
#define BK 32
#define LDK 40   // padded LDS leading dim for tiled GEMMs

typedef short bf16x8 __attribute__((ext_vector_type(8)));
typedef float floatx4 __attribute__((ext_vector_type(4)));

__device__ __forceinline__ unsigned short f2b(float f) {
    union { float f; unsigned int i; } v;
    v.f = f;
    unsigned int lsb = (v.i >> 16) & 1u;
    v.i += 0x7fffu + lsb;            // round-to-nearest-even
    return (unsigned short)(v.i >> 16);
}

__device__ __forceinline__ float b2f(unsigned short u) {
    union { unsigned int i; float f; } v;
    v.i = ((unsigned int)u) << 16;
    return v.f;
}

__device__ __forceinline__ bf16x8 pack8(float4 a, float4 b) {
    bf16x8 r;
    r[0] = (short)f2b(a.x); r[1] = (short)f2b(a.y);
    r[2] = (short)f2b(a.z); r[3] = (short)f2b(a.w);
    r[4] = (short)f2b(b.x); r[5] = (short)f2b(b.y);
    r[6] = (short)f2b(b.z); r[7] = (short)f2b(b.w);
    return r;
}

// ---- fused: claim marked nodes + in-degree over all edges ----
__global__ __launch_bounds__(256) void prep1_k(const int* __restrict__ agent_idx,
                                               int* __restrict__ nid,
                                               const int* __restrict__ dst,
                                               int* __restrict__ deg) {
    int i = blockIdx.x * 256 + threadIdx.x;
    if (i < N_AGENTS) atomicCAS(&nid[agent_idx[i]], -1, i);
    if (i < N_EDGES) atomicAdd(&deg[dst[i]], 1);
}

// ---- fused: compact ids + bump-alloc row bases + dis = rsqrt(deg+1) ----
__global__ __launch_bounds__(256) void prep2_k(int* __restrict__ nid,
                                               int* __restrict__ list,
                                               int* __restrict__ cnt,
                                               const int* __restrict__ deg,
                                               int* __restrict__ rowbeg,
                                               int* __restrict__ etot,
                                               float* __restrict__ dis) {
    int i = blockIdx.x * 256 + threadIdx.x;
    if (i < N_NODES) {
        int d = deg[i];
        dis[i] = rsqrtf((float)(d + 1));
        if (nid[i] != -1) {
            int c = atomicAdd(cnt, 1);
            nid[i] = c;
            list[c] = i;
            rowbeg[c] = atomicAdd(etot, d);
        }
    }
}

// ---- fill buckets: for needed dsts, append src to its row ----
__global__ __launch_bounds__(256) void fill_k(const int* __restrict__ src,
                                              const int* __restrict__ dst,
                                              const int* __restrict__ nid,
                                              const int* __restrict__ rowbeg,
                                              int* __restrict__ fill,
                                              int* __restrict__ ebuf) {
    int e = blockIdx.x * 256 + threadIdx.x;
    if (e >= N_EDGES) return;
    int c = nid[dst[e]];
    if (c < 0) return;
    int p = atomicAdd(&fill[c], 1);
    ebuf[rowbeg[c] + p] = src[e];
}

// ---- weight transpose+convert via LDS tiles: f32 [K,N] -> bf16 [N,K] ----
__global__ __launch_bounds__(256) void wtr_k(const float* __restrict__ Wgcn,
                                             const float* __restrict__ W1,
                                             const float* __restrict__ W2,
                                             const float* __restrict__ Wmu,
                                             unsigned short* __restrict__ wgcn_t,
                                             unsigned short* __restrict__ w1_t,
                                             unsigned short* __restrict__ w2_t,
                                             unsigned short* __restrict__ wmu_t) {
    __shared__ unsigned short Ts[64][72];
    int b = blockIdx.x;
    const float* src; unsigned short* dst; int K, N, tk, tn;
    if (b < 8)        { src = Wgcn; dst = wgcn_t; K = IN_DIM; N = HID;  tk = b >> 2;        tn = b & 3; }
    else if (b < 72)  { int bb = b - 8;  src = W1; dst = w1_t; K = HID;  N = FC1;  tk = bb >> 4; tn = bb & 15; }
    else if (b < 200) { int bb = b - 72; src = W2; dst = w2_t; K = FC1;  N = FC2;  tk = bb >> 3; tn = bb & 7; }
    else              { int bb = b - 200; src = Wmu; dst = wmu_t; K = FC2; N = N_ACT; tk = bb;   tn = 0; }
    int k0 = tk * 64, n0 = tn * 64;
    int tid = threadIdx.x;
    int r  = tid >> 2;
    int cc = (tid & 3) * 16;
    if (n0 + cc < N) {
        const float* p = src + (size_t)(k0 + r) * N + n0 + cc;
        #pragma unroll
        for (int i = 0; i < 16; i += 4) {
            float4 v = *(const float4*)(p + i);
            Ts[r][cc + i + 0] = f2b(v.x);
            Ts[r][cc + i + 1] = f2b(v.y);
            Ts[r][cc + i + 2] = f2b(v.z);
            Ts[r][cc + i + 3] = f2b(v.w);
        }
    }
    __syncthreads();
    int n = tid >> 2;
    if (n0 + n < N) {
        bf16x8 o0, o1;
        #pragma unroll
        for (int i = 0; i < 8; ++i) o0[i] = (short)Ts[cc + i][n];
        #pragma unroll
        for (int i = 0; i < 8; ++i) o1[i] = (short)Ts[cc + 8 + i][n];
        unsigned short* q = dst + (size_t)(n0 + n) * K + k0 + cc;
        *(bf16x8*)q = o0;
        *(bf16x8*)(q + 8) = o1;
    }
}

// ---- accumulate per needed node: sum in-edges + self-loop + bias, relu -> bf16 ----
__global__ __launch_bounds__(256) void accum_k(const int* __restrict__ cntp,
                                               const int* __restrict__ list,
                                               const int* __restrict__ rowbeg,
                                               const int* __restrict__ deg,
                                               const int* __restrict__ ebuf,
                                               const float* __restrict__ dis,
                                               const unsigned short* __restrict__ xw,
                                               const float* __restrict__ bgcn,
                                               unsigned short* __restrict__ h_node) {
    int c = blockIdx.x;
    if (c >= *cntp) return;
    int n = list[c];
    int lane = threadIdx.x & 63;
    int wave = threadIdx.x >> 6;
    int beg = rowbeg[c];
    int end = beg + deg[n];
    float dn = dis[n];
    floatx4 acc = {0.0f, 0.0f, 0.0f, 0.0f};
    for (int i = beg + wave; i < end; i += 4) {
        int s = ebuf[i];
        float w = dis[s] * dn;
        ushort4 u = *(const ushort4*)(xw + (size_t)s * HID + lane * 4);
        acc.x += w * b2f(u.x);
        acc.y += w * b2f(u.y);
        acc.z += w * b2f(u.z);
        acc.w += w * b2f(u.w);
    }
    __shared__ float part[4][HID];
    part[wave][lane * 4 + 0] = acc.x;
    part[wave][lane * 4 + 1] = acc.y;
    part[wave][lane * 4 + 2] = acc.z;
    part[wave][lane * 4 + 3] = acc.w;
    __syncthreads();
    int t = threadIdx.x;
    float v = part[0][t] + part[1][t] + part[2][t] + part[3][t];
    v += b2f(xw[(size_t)n * HID + t]) * dn * dn + bgcn[t];
    if (v < 0.0f) v = 0.0f;
    h_node[(size_t)c * HID + t] = f2b(v);
}

// ---- tiled GEMM (bf16 A): C = A @ Bt^T, bf16(v + bias) out ----
__global__ __launch_bounds__(256) void gemm_tiled_k(const unsigned short* __restrict__ A,
                                                    const unsigned short* __restrict__ Bt,
                                                    const float* __restrict__ bias,
                                                    unsigned short* __restrict__ outb,
                                                    int M, int N, int K) {
    __shared__ unsigned short As[BM][LDK];
    __shared__ unsigned short Bs[BN][LDK];

    int tn = blockIdx.x;
    int tm = blockIdx.y;
    int tid = threadIdx.x;
    int lane = tid & 63;
    int wave = tid >> 6;
    int wm = wave >> 1, wn = wave & 1;
    int r16 = lane & 15, quad = lane >> 4;

    int srow = tid >> 2;
    int scol = (tid & 3) * 8;
    const unsigned short* pa0 = A + (size_t)(tm * BM + srow) * K + scol;
    const unsigned short* pa1 = A + (size_t)(tm * BM + srow + 64) * K + scol;
    const unsigned short* pb0 = Bt + (size_t)(tn * BN + srow) * K + scol;
    const unsigned short* pb1 = Bt + (size_t)(tn * BN + srow + 64) * K + scol;

    floatx4 acc[4][4];
    #pragma unroll
    for (int i = 0; i < 4; ++i)
        #pragma unroll
        for (int j = 0; j < 4; ++j)
            acc[i][j] = (floatx4){0.0f, 0.0f, 0.0f, 0.0f};

    bf16x8 ra0 = *(const bf16x8*)pa0;
    bf16x8 ra1 = *(const bf16x8*)pa1;
    bf16x8 rb0 = *(const bf16x8*)pb0;
    bf16x8 rb1 = *(const bf16x8*)pb1;

    for (int k0 = 0; k0 < K; k0 += BK) {
        *(bf16x8*)&As[srow][scol]      = ra0;
        *(bf16x8*)&As[srow + 64][scol] = ra1;
        *(bf16x8*)&Bs[srow][scol]      = rb0;
        *(bf16x8*)&Bs[srow + 64][scol] = rb1;
        __syncthreads();

        if (k0 + BK < K) {
            ra0 = *(const bf16x8*)(pa0 + k0 + BK);
            ra1 = *(const bf16x8*)(pa1 + k0 + BK);
            rb0 = *(const bf16x8*)(pb0 + k0 + BK);
            rb1 = *(const bf16x8*)(pb1 + k0 + BK);
        }

        bf16x8 af[4], bfr[4];
        #pragma unroll
        for (int i = 0; i < 4; ++i)
            af[i] = *(const bf16x8*)&As[wm * 64 + i * 16 + r16][quad * 8];
        #pragma unroll
        for (int j = 0; j < 4; ++j)
            bfr[j] = *(const bf16x8*)&Bs[wn * 64 + j * 16 + r16][quad * 8];
        #pragma unroll
        for (int i = 0; i < 4; ++i)
            #pragma unroll
            for (int j = 0; j < 4; ++j)
                acc[i][j] = __builtin_amdgcn_mfma_f32_16x16x32_bf16(af[i], bfr[j], acc[i][j], 0, 0, 0);
        __syncthreads();
    }

    #pragma unroll
    for (int j = 0; j < 4; ++j) {
        int ocol = tn * BN + wn * 64 + j * 16 + r16;
        float bv = bias[ocol];
        #pragma unroll
        for (int i = 0; i < 4; ++i) {
            int orow = tm * BM + wm * 64 + i * 16 + quad * 4;
            #pragma unroll
            for (int r = 0; r < 4; ++r)
                outb[(size_t)(orow + r) * N + ocol] = f2b(acc[i][j][r] + bv);
        }
    }
}

// ---- tiled GEMM, A rows gathered indirectly (FC1 + agent gather fused) ----
__global__ __launch_bounds__(256) void gemm_tiled_gather_k(const unsigned short* __restrict__ h_node,
                                                           const int* __restrict__ agent,
                                                           const int* __restrict__ nid,
                                                           const unsigned short* __restrict__ Bt,
                                                           const float* __restrict__ bias,
                                                           unsigned short* __restrict__ outb,
                                                           int M, int N, int K) {
    __shared__ unsigned short As[BM][LDK];
    __shared__ unsigned short Bs[BN][LDK];

    int tn = blockIdx.x;
    int tm = blockIdx.y;
    int tid = threadIdx.x;
    int lane = tid & 63;
    int wave = tid >> 6;
    int wm = wave >> 1, wn = wave & 1;
    int r16 = lane & 15, quad = lane >> 4;

    int srow = tid >> 2;
    int scol = (tid & 3) * 8;
    int c0 = nid[agent[tm * BM + srow]];
    int c1 = nid[agent[tm * BM + srow + 64]];
    const unsigned short* pa0 = h_node + (size_t)c0 * K + scol;
    const unsigned short* pa1 = h_node + (size_t)c1 * K + scol;
    const unsigned short* pb0 = Bt + (size_t)(tn * BN + srow) * K + scol;
    const unsigned short* pb1 = Bt + (size_t)(tn * BN + srow + 64) * K + scol;

    floatx4 acc[4][4];
    #pragma unroll
    for (int i = 0; i < 4; ++i)
        #pragma unroll
        for (int j = 0; j < 4; ++j)
            acc[i][j] = (floatx4){0.0f, 0.0f, 0.0f, 0.0f};

    bf16x8 ra0 = *(const bf16x8*)pa0;
    bf16x8 ra1 = *(const bf16x8*)pa1;
    bf16x8 rb0 = *(const bf16x8*)pb0;
    bf16x8 rb1 = *(const bf16x8*)pb1;

    for (int k0 = 0; k0 < K; k0 += BK) {
        *(bf16x8*)&As[srow][scol]      = ra0;
        *(bf16x8*)&As[srow + 64][scol] = ra1;
        *(bf16x8*)&Bs[srow][scol]      = rb0;
        *(bf16x8*)&Bs[srow + 64][scol] = rb1;
        __syncthreads();

        if (k0 + BK < K) {
            ra0 = *(const bf16x8*)(pa0 + k0 + BK);
            ra1 = *(const bf16x8*)(pa1 + k0 + BK);
            rb0 = *(const bf16x8*)(pb0 + k0 + BK);
            rb1 = *(const bf16x8*)(pb1 + k0 + BK);
        }

        bf16x8 af[4], bfr[4];
        #pragma unroll
        for (int i = 0; i < 4; ++i)
            af[i] = *(const bf16x8*)&As[wm * 64 + i * 16 + r16][quad * 8];
        #pragma unroll
        for (int j = 0; j < 4; ++j)
            bfr[j] = *(const bf16x8*)&Bs[wn * 64 + j * 16 + r16][quad * 8];
        #pragma unroll
        for (int i = 0; i < 4; ++i)
            #pragma unroll
            for (int j = 0; j < 4; ++j)
                acc[i][j] = __builtin_amdgcn_mfma_f32_16x16x32_bf16(af[i], bfr[j], acc[i][j], 0, 0, 0);
        __syncthreads();
    }

    #pragma unroll
    for (int j = 0; j < 4; ++j) {
        int ocol = tn * BN + wn * 64 + j * 16 + r16;
        float bv = bias[ocol];
        #pragma unroll
        for (int i = 0; i < 4; ++i) {
            int orow = tm * BM + wm * 64 + i * 16 + quad * 4;
            #pragma unroll
            for (int r = 0; r < 4; ++r)
                outb[(size_t)(orow + r) * N + ocol] = f2b(acc[i][j][r] + bv);
        }
    }
}

// ---- tiled GEMM with f32 A (converts during LDS staging): xw = x @ Wgcn ----
__global__ __launch_bounds__(256) void gemm_tiled_f32a_k(const float* __restrict__ A,
                                                         const unsigned short* __restrict__ Bt,
                                                         unsigned short* __restrict__ outb,
                                                         int M, int N, int K) {
    __shared__ unsigned short As[BM][LDK];
    __shared__ unsigned short Bs[BN][LDK];

    int tn = blockIdx.x;
    int tm = blockIdx.y;
    int tid = threadIdx.x;
    int lane = tid & 63;
    int wave = tid >> 6;
    int wm = wave >> 1, wn = wave & 1;
    int r16 = lane & 15, quad = lane >> 4;

    int srow = tid >> 2;
    int scol = (tid & 3) * 8;
    int ar0 = tm * BM + srow;        if (ar0 > M - 1) ar0 = M - 1;
    int ar1 = tm * BM + srow + 64;   if (ar1 > M - 1) ar1 = M - 1;
    const float* pa0 = A + (size_t)ar0 * K + scol;
    const float* pa1 = A + (size_t)ar1 * K + scol;
    const unsigned short* pb0 = Bt + (size_t)(tn * BN + srow) * K + scol;
    const unsigned short* pb1 = Bt + (size_t)(tn * BN + srow + 64) * K + scol;

    floatx4 acc[4][4];
    #pragma unroll
    for (int i = 0; i < 4; ++i)
        #pragma unroll
        for (int j = 0; j < 4; ++j)
            acc[i][j] = (floatx4){0.0f, 0.0f, 0.0f, 0.0f};

    float4 ra0a = *(const float4*)pa0, ra0b = *(const float4*)(pa0 + 4);
    float4 ra1a = *(const float4*)pa1, ra1b = *(const float4*)(pa1 + 4);
    bf16x8 rb0 = *(const bf16x8*)pb0;
    bf16x8 rb1 = *(const bf16x8*)pb1;

    for (int k0 = 0; k0 < K; k0 += BK) {
        *(bf16x8*)&As[srow][scol]      = pack8(ra0a, ra0b);
        *(bf16x8*)&As[srow + 64][scol] = pack8(ra1a, ra1b);
        *(bf16x8*)&Bs[srow][scol]      = rb0;
        *(bf16x8*)&Bs[srow + 64][scol] = rb1;
        __syncthreads();

        if (k0 + BK < K) {
            ra0a = *(const float4*)(pa0 + k0 + BK);
            ra0b = *(const float4*)(pa0 + k0 + BK + 4);
            ra1a = *(const float4*)(pa1 + k0 + BK);
            ra1b = *(const float4*)(pa1 + k0 + BK + 4);
            rb0 = *(const bf16x8*)(pb0 + k0 + BK);
            rb1 = *(const bf16x8*)(pb1 + k0 + BK);
        }

        bf16x8 af[4], bfr[4];
        #pragma unroll
        for (int i = 0; i < 4; ++i)
            af[i] = *(const bf16x8*)&As[wm * 64 + i * 16 + r16][quad * 8];
        #pragma unroll
        for (int j = 0; j < 4; ++j)
            bfr[j] = *(const bf16x8*)&Bs[wn * 64 + j * 16 + r16][quad * 8];
        #pragma unroll
        for (int i = 0; i < 4; ++i)
            #pragma unroll
            for (int j = 0; j < 4; ++j)
                acc[i][j] = __builtin_amdgcn_mfma_f32_16x16x32_bf16(af[i], bfr[j], acc[i][j], 0, 0, 0);
        __syncthreads();
    }

    #pragma unroll
    for (int j = 0; j < 4; ++j) {
        int ocol = tn * BN + wn * 64 + j * 16 + r16;
        #pragma unroll
        for (int i = 0; i < 4; ++i) {
            int orow_base = tm * BM + wm * 64 + i * 16 + quad * 4;
            #pragma unroll
            for (int r = 0; r < 4; ++r) {
                int orow = orow_base + r;
                if (orow < M)
                    outb[(size_t)orow * N + ocol] = f2b(acc[i][j][r]);
            }
        }
    }
}

// ---- single-pass row LayerNorm (+affine) + relu, bf16 in -> bf16 out (FC1) ----
__global__ __launch_bounds__(256) void ln_relu_k(const unsigned short* __restrict__ z,
                                                 const float* __restrict__ g,
                                                 const float* __restrict__ be,
                                                 unsigned short* __restrict__ out, int L) {
    size_t base = (size_t)blockIdx.x * L;
    int nc = L >> 8;
    float vreg[4];
    float s = 0.0f, s2 = 0.0f;
    for (int i = 0; i < nc; ++i) {
        float v = b2f(z[base + i * 256 + threadIdx.x]);
        vreg[i] = v;
        s += v;
        s2 += v * v;
    }
    for (int off = 32; off > 0; off >>= 1) {
        s += __shfl_down(s, off);
        s2 += __shfl_down(s2, off);
    }
    __shared__ float red[8];
    int wave = threadIdx.x >> 6;
    int lane = threadIdx.x & 63;
    if (lane == 0) { red[wave] = s; red[4 + wave] = s2; }
    __syncthreads();
    s  = red[0] + red[1] + red[2] + red[3];
    s2 = red[4] + red[5] + red[6] + red[7];
    float invL = 1.0f / (float)L;
    float mean = s * invL;
    float var = s2 * invL - mean * mean;
    float inv = rsqrtf(var + 1e-5f);
    for (int i = 0; i < nc; ++i) {
        int c = i * 256 + threadIdx.x;
        float v = (vreg[i] - mean) * inv * g[c] + be[c];
        if (v < 0.0f) v = 0.0f;
        out[base + c] = f2b(v);
    }
}

// ---- fused LN2 + ReLU + head, 16 rows/block (512 blocks) ----
// Phase 1: LN for 16 rows (16 lanes/row); normalized bf16 tile -> LDS.
// Phase 2: MFMA head vs bf16 wmu_t (16 KB/block, not 32 KB x 8192!), reduce, sigmoid.
__global__ __launch_bounds__(256) void ln2head_k(const unsigned short* __restrict__ z,
                                                 const float* __restrict__ g2,
                                                 const float* __restrict__ be2,
                                                 const unsigned short* __restrict__ wmu_t,
                                                 const float* __restrict__ bmu,
                                                 float* __restrict__ out) {
    __shared__ unsigned short Hs[16][520];
    __shared__ float hred[4][64][4];
    int tid = threadIdx.x;
    int tm = blockIdx.x;
    // ---- phase 1: LN per row; row = tid>>4, 16 lanes per row, 32 elems each ----
    {
        int row = tid >> 4;
        int sub = tid & 15;
        const unsigned short* src = z + (size_t)(tm * 16 + row) * FC2 + sub * 32;
        bf16x8 a0 = *(const bf16x8*)(src);
        bf16x8 a1 = *(const bf16x8*)(src + 8);
        bf16x8 a2 = *(const bf16x8*)(src + 16);
        bf16x8 a3 = *(const bf16x8*)(src + 24);
        float v[32];
        #pragma unroll
        for (int i = 0; i < 8; ++i) {
            v[i]      = b2f((unsigned short)a0[i]);
            v[8 + i]  = b2f((unsigned short)a1[i]);
            v[16 + i] = b2f((unsigned short)a2[i]);
            v[24 + i] = b2f((unsigned short)a3[i]);
        }
        float s = 0.0f, s2 = 0.0f;
        #pragma unroll
        for (int i = 0; i < 32; ++i) { s += v[i]; s2 += v[i] * v[i]; }
        #pragma unroll
        for (int m = 1; m < 16; m <<= 1) {      // stays within the 16-lane row group
            s  += __shfl_xor(s, m);
            s2 += __shfl_xor(s2, m);
        }
        float mean = s * (1.0f / FC2);
        float var = s2 * (1.0f / FC2) - mean * mean;
        float inv = rsqrtf(var + 1e-5f);
        #pragma unroll
        for (int i = 0; i < 32; ++i) {
            int c = sub * 32 + i;
            float w = (v[i] - mean) * inv * g2[c] + be2[c];
            if (w < 0.0f) w = 0.0f;
            Hs[row][c] = f2b(w);
        }
    }
    __syncthreads();
    // ---- phase 2: head MFMA; wave w covers K-slice [w*128, w*128+128) ----
    int lane = tid & 63, wave = tid >> 6;
    int r16 = lane & 15, quad = lane >> 4;
    floatx4 acc = {0.0f, 0.0f, 0.0f, 0.0f};
    #pragma unroll
    for (int st = 0; st < 4; ++st) {
        bf16x8 a = *(const bf16x8*)&Hs[r16][wave * 128 + st * 32 + quad * 8];
        bf16x8 b = *(const bf16x8*)(wmu_t + (size_t)r16 * FC2 + wave * 128 + st * 32 + quad * 8);
        acc = __builtin_amdgcn_mfma_f32_16x16x32_bf16(a, b, acc, 0, 0, 0);
    }
    #pragma unroll
    for (int r = 0; r < 4; ++r) hred[wave][lane][r] = acc[r];
    __syncthreads();
    if (wave == 0) {
        #pragma unroll
        for (int r = 0; r < 4; ++r) {
            float v = hred[0][lane][r] + hred[1][lane][r] + hred[2][lane][r] + hred[3][lane][r];
            v += bmu[r16];
            v = 1.0f / (1.0f + expf(-v));
            out[(size_t)(tm * 16 + quad * 4 + r) * N_ACT + r16] = v;
        }
    }
}

extern "C" void kernel_launch(void* const* d_in, const int* in_sizes, int n_in,
                              void* d_out, int out_size, void* d_ws, size_t ws_size,
                              hipStream_t stream) {
    const float* x    = (const float*)d_in[0];
    const int*   ei   = (const int*)d_in[1];
    const int*   agent= (const int*)d_in[2];
    const float* Wgcn = (const float*)d_in[3];
    const float* bgcn = (const float*)d_in[4];
    const float* W1   = (const float*)d_in[5];
    const float* b1   = (const float*)d_in[6];
    const float* g1   = (const float*)d_in[7];
    const float* be1  = (const float*)d_in[8];
    const float* W2   = (const float*)d_in[9];
    const float* b2   = (const float*)d_in[10];
    const float* g2   = (const float*)d_in[11];
    const float* be2  = (const float*)d_in[12];
    const float* Wmu  = (const float*)d_in[13];
    const float* bmu  = (const float*)d_in[14];
    float* out = (float*)d_out;

    const int* srcp = ei;
    const int* dstp = ei + N_EDGES;

    // workspace layout (256B aligned). Zero-init region contiguous: deg|fill|cnt|etot.
    char* ws = (char*)d_ws;
    size_t off = 0;
    char* zero_base = ws;
    int* deg = (int*)(ws + off);     off += ((size_t)N_NODES * 4 + 255) & ~(size_t)255;
    int* fill = (int*)(ws + off);    off += ((size_t)N_AGENTS * 4 + 255) & ~(size_t)255;
    int* cnt = (int*)(ws + off);     off += 256;
    int* etot = (int*)(ws + off);    off += 256;
    size_t zero_bytes = off;
    int* nid = (int*)(ws + off);     off += ((size_t)N_NODES * 4 + 255) & ~(size_t)255;
    float* dis = (float*)(ws + off); off += ((size_t)N_NODES * 4 + 255) & ~(size_t)255;
    int* list = (int*)(ws + off);    off += ((size_t)N_AGENTS * 4 + 255) & ~(size_t)255;
    int* rowbeg = (int*)(ws + off);  off += ((size_t)N_AGENTS * 4 + 255) & ~(size_t)255;
    int* ebuf = (int*)(ws + off);    off += ((size_t)N_EDGES * 4 + 255) & ~(size_t)255;
    unsigned short* wgcn_t = (unsigned short*)(ws + off); off += ((size_t)IN_DIM * HID * 2 + 255) & ~(size_t)255;
    unsigned short* w1_t   = (unsigned short*)(ws + off); off += ((size_t)HID * FC1 * 2 + 255) & ~(size_t)255;
    unsigned short* w2_t   = (unsigned short*)(ws + off); off += ((size_t)FC1 * FC2 * 2 + 255) & ~(size_t)255;
    unsigned short* wmu_t  = (unsigned short*)(ws + off); off += ((size_t)FC2 * N_ACT * 2 + 255) & ~(size_t)255;
    unsigned short* xw     = (unsigned short*)(ws + off); off += ((size_t)N_NODES * HID * 2 + 255) & ~(size_t)255;
    unsigned short* h_node = (unsigned short*)(ws + off); off += ((size_t)N_AGENTS * HID * 2 + 255) & ~(size_t)255;
    unsigned short* zb = (unsigned short*)(ws + off);     off += ((size_t)N_AGENTS * FC1 * 2 + 255) & ~(size_t)255;
    unsigned short* h1 = (unsigned short*)(ws + off);     off += ((size_t)N_AGENTS * FC1 * 2 + 255) & ~(size_t)255;

    // ---- init via memset: zeros + nid=-1 ----
    hipMemsetAsync(zero_base, 0, zero_bytes, stream);
    hipMemsetAsync(nid, 0xFF, (size_t)N_NODES * 4, stream);

    // ---- graph prep / CSR build ----
    prep1_k<<<(N_EDGES + 255) / 256, 256, 0, stream>>>(agent, nid, dstp, deg);
    prep2_k<<<(N_NODES + 255) / 256, 256, 0, stream>>>(nid, list, cnt, deg, rowbeg, etot, dis);
    fill_k<<<(N_EDGES + 255) / 256, 256, 0, stream>>>(srcp, dstp, nid, rowbeg, fill, ebuf);

    // ---- weight transpose+convert (incl. wmu_t for the head) ----
    wtr_k<<<208, 256, 0, stream>>>(Wgcn, W1, W2, Wmu, wgcn_t, w1_t, w2_t, wmu_t);

    // xw = x @ W_gcn
    {
        dim3 grid(HID / BN, (N_NODES + BM - 1) / BM);
        gemm_tiled_f32a_k<<<grid, 256, 0, stream>>>(x, wgcn_t, xw, N_NODES, HID, IN_DIM);
    }

    // per-needed-node aggregation
    accum_k<<<N_AGENTS, 256, 0, stream>>>(cnt, list, rowbeg, deg, ebuf, dis, xw, bgcn, h_node);

    // FC1 (agent gather fused) -> LN+relu
    {
        dim3 grid(FC1 / BN, N_AGENTS / BM);
        gemm_tiled_gather_k<<<grid, 256, 0, stream>>>(h_node, agent, nid, w1_t, b1, zb,
                                                      N_AGENTS, FC1, HID);
        ln_relu_k<<<N_AGENTS, 256, 0, stream>>>(zb, g1, be1, h1, FC1);
    }

    // FC2 -> fused LN + head (16 rows/block)
    {
        dim3 grid(FC2 / BN, N_AGENTS / BM);
        gemm_tiled_k<<<grid, 256, 0, stream>>>(h1, w2_t, b2, zb, N_AGENTS, FC2, FC1);
        ln2head_k<<<N_AGENTS / 16, 256, 0, stream>>>(zb, g2, be2, wmu_t, bmu, out);
    }
}

// Round 12
// 239.980 us; speedup vs baseline: 1.2015x; 1.0593x over previous
//
#include <hip/hip_runtime.h>
#include <hip/hip_bf16.h>
#include <math.h>

#define N_NODES  50000
#define N_EDGES  800000
#define IN_DIM   128
#define HID      256
#define FC1      1024
#define FC2      512
#define N_ACT    16
#define N_AGENTS 8192

#define BM 128
#define BN 128
#define BK 32
#define LDK 40   // padded LDS leading dim for tiled GEMMs

typedef short bf16x8 __attribute__((ext_vector_type(8)));
typedef float floatx4 __attribute__((ext_vector_type(4)));

__device__ __forceinline__ unsigned short f2b(float f) {
    union { float f; unsigned int i; } v;
    v.f = f;
    unsigned int lsb = (v.i >> 16) & 1u;
    v.i += 0x7fffu + lsb;            // round-to-nearest-even
    return (unsigned short)(v.i >> 16);
}

__device__ __forceinline__ float b2f(unsigned short u) {
    union { unsigned int i; float f; } v;
    v.i = ((unsigned int)u) << 16;
    return v.f;
}

// ---- fused: claim marked nodes + in-degree over all edges ----
__global__ __launch_bounds__(256) void prep1_k(const int* __restrict__ agent_idx,
                                               int* __restrict__ nid,
                                               const int* __restrict__ dst,
                                               int* __restrict__ deg) {
    int i = blockIdx.x * 256 + threadIdx.x;
    if (i < N_AGENTS) atomicCAS(&nid[agent_idx[i]], -1, i);
    if (i < N_EDGES) atomicAdd(&deg[dst[i]], 1);
}

// ---- fused: compact ids + bump-alloc row bases + dis = rsqrt(deg+1) ----
__global__ __launch_bounds__(256) void prep2_k(int* __restrict__ nid,
                                               int* __restrict__ list,
                                               int* __restrict__ cnt,
                                               const int* __restrict__ deg,
                                               int* __restrict__ rowbeg,
                                               int* __restrict__ etot,
                                               float* __restrict__ dis) {
    int i = blockIdx.x * 256 + threadIdx.x;
    if (i < N_NODES) {
        int d = deg[i];
        dis[i] = rsqrtf((float)(d + 1));
        if (nid[i] != -1) {
            int c = atomicAdd(cnt, 1);
            nid[i] = c;
            list[c] = i;
            rowbeg[c] = atomicAdd(etot, d);
        }
    }
}

// ---- fill buckets: for needed dsts, append src to its row ----
__global__ __launch_bounds__(256) void fill_k(const int* __restrict__ src,
                                              const int* __restrict__ dst,
                                              const int* __restrict__ nid,
                                              const int* __restrict__ rowbeg,
                                              int* __restrict__ fill,
                                              int* __restrict__ ebuf) {
    int e = blockIdx.x * 256 + threadIdx.x;
    if (e >= N_EDGES) return;
    int c = nid[dst[e]];
    if (c < 0) return;
    int p = atomicAdd(&fill[c], 1);
    ebuf[rowbeg[c] + p] = src[e];
}

// ---- weight transpose+convert via LDS tiles: f32 [K,N] -> bf16 [N,K] ----
__global__ __launch_bounds__(256) void wtr_k(const float* __restrict__ Wgcn,
                                             const float* __restrict__ W1,
                                             const float* __restrict__ W2,
                                             const float* __restrict__ Wmu,
                                             unsigned short* __restrict__ wgcn_t,
                                             unsigned short* __restrict__ w1_t,
                                             unsigned short* __restrict__ w2_t,
                                             unsigned short* __restrict__ wmu_t) {
    __shared__ unsigned short Ts[64][72];
    int b = blockIdx.x;
    const float* src; unsigned short* dst; int K, N, tk, tn;
    if (b < 8)        { src = Wgcn; dst = wgcn_t; K = IN_DIM; N = HID;  tk = b >> 2;        tn = b & 3; }
    else if (b < 72)  { int bb = b - 8;  src = W1; dst = w1_t; K = HID;  N = FC1;  tk = bb >> 4; tn = bb & 15; }
    else if (b < 200) { int bb = b - 72; src = W2; dst = w2_t; K = FC1;  N = FC2;  tk = bb >> 3; tn = bb & 7; }
    else              { int bb = b - 200; src = Wmu; dst = wmu_t; K = FC2; N = N_ACT; tk = bb;   tn = 0; }
    int k0 = tk * 64, n0 = tn * 64;
    int tid = threadIdx.x;
    int r  = tid >> 2;
    int cc = (tid & 3) * 16;
    if (n0 + cc < N) {
        const float* p = src + (size_t)(k0 + r) * N + n0 + cc;
        #pragma unroll
        for (int i = 0; i < 16; i += 4) {
            float4 v = *(const float4*)(p + i);
            Ts[r][cc + i + 0] = f2b(v.x);
            Ts[r][cc + i + 1] = f2b(v.y);
            Ts[r][cc + i + 2] = f2b(v.z);
            Ts[r][cc + i + 3] = f2b(v.w);
        }
    }
    __syncthreads();
    int n = tid >> 2;
    if (n0 + n < N) {
        bf16x8 o0, o1;
        #pragma unroll
        for (int i = 0; i < 8; ++i) o0[i] = (short)Ts[cc + i][n];
        #pragma unroll
        for (int i = 0; i < 8; ++i) o1[i] = (short)Ts[cc + 8 + i][n];
        unsigned short* q = dst + (size_t)(n0 + n) * K + k0 + cc;
        *(bf16x8*)q = o0;
        *(bf16x8*)(q + 8) = o1;
    }
}

// ---- aggregate raw x rows per needed node (GCN aggregation BEFORE the weight
//      multiply — linearity lets us shrink the GCN GEMM from 50k to 8k rows).
//      agg[c] = sum_edges dis[s]*dis[n]*x[s] + dis[n]^2*x[n]  -> bf16 [c][128]
__global__ __launch_bounds__(256) void accumx_k(const int* __restrict__ cntp,
                                                const int* __restrict__ list,
                                                const int* __restrict__ rowbeg,
                                                const int* __restrict__ deg,
                                                const int* __restrict__ ebuf,
                                                const float* __restrict__ dis,
                                                const float* __restrict__ x,
                                                unsigned short* __restrict__ agg) {
    int c = blockIdx.x;
    if (c >= *cntp) return;
    int n = list[c];
    int lane = threadIdx.x & 63;
    int wave = threadIdx.x >> 6;
    int beg = rowbeg[c];
    int end = beg + deg[n];
    float dn = dis[n];
    float ax = 0.0f, ay = 0.0f;
    for (int i = beg + wave; i < end; i += 4) {
        int s = ebuf[i];
        float w = dis[s] * dn;
        float2 u = *(const float2*)(x + (size_t)s * IN_DIM + lane * 2);
        ax += w * u.x;
        ay += w * u.y;
    }
    __shared__ float part[4][IN_DIM];
    part[wave][lane * 2 + 0] = ax;
    part[wave][lane * 2 + 1] = ay;
    __syncthreads();
    int t = threadIdx.x;
    if (t < IN_DIM) {
        float v = part[0][t] + part[1][t] + part[2][t] + part[3][t];
        v += dn * dn * x[(size_t)n * IN_DIM + t];
        agg[(size_t)c * IN_DIM + t] = f2b(v);
    }
}

// ---- tiled GEMM (bf16 A): C = A @ Bt^T, bf16(v + bias [, relu]) out ----
// mode 0: bf16(v + bias);  mode 1: bf16(relu(v + bias))  (GCN layer)
__global__ __launch_bounds__(256) void gemm_tiled_k(const unsigned short* __restrict__ A,
                                                    const unsigned short* __restrict__ Bt,
                                                    const float* __restrict__ bias,
                                                    unsigned short* __restrict__ outb,
                                                    int M, int N, int K, int mode) {
    __shared__ unsigned short As[BM][LDK];
    __shared__ unsigned short Bs[BN][LDK];

    int tn = blockIdx.x;
    int tm = blockIdx.y;
    int tid = threadIdx.x;
    int lane = tid & 63;
    int wave = tid >> 6;
    int wm = wave >> 1, wn = wave & 1;
    int r16 = lane & 15, quad = lane >> 4;

    int srow = tid >> 2;
    int scol = (tid & 3) * 8;
    const unsigned short* pa0 = A + (size_t)(tm * BM + srow) * K + scol;
    const unsigned short* pa1 = A + (size_t)(tm * BM + srow + 64) * K + scol;
    const unsigned short* pb0 = Bt + (size_t)(tn * BN + srow) * K + scol;
    const unsigned short* pb1 = Bt + (size_t)(tn * BN + srow + 64) * K + scol;

    floatx4 acc[4][4];
    #pragma unroll
    for (int i = 0; i < 4; ++i)
        #pragma unroll
        for (int j = 0; j < 4; ++j)
            acc[i][j] = (floatx4){0.0f, 0.0f, 0.0f, 0.0f};

    bf16x8 ra0 = *(const bf16x8*)pa0;
    bf16x8 ra1 = *(const bf16x8*)pa1;
    bf16x8 rb0 = *(const bf16x8*)pb0;
    bf16x8 rb1 = *(const bf16x8*)pb1;

    for (int k0 = 0; k0 < K; k0 += BK) {
        *(bf16x8*)&As[srow][scol]      = ra0;
        *(bf16x8*)&As[srow + 64][scol] = ra1;
        *(bf16x8*)&Bs[srow][scol]      = rb0;
        *(bf16x8*)&Bs[srow + 64][scol] = rb1;
        __syncthreads();

        if (k0 + BK < K) {
            ra0 = *(const bf16x8*)(pa0 + k0 + BK);
            ra1 = *(const bf16x8*)(pa1 + k0 + BK);
            rb0 = *(const bf16x8*)(pb0 + k0 + BK);
            rb1 = *(const bf16x8*)(pb1 + k0 + BK);
        }

        bf16x8 af[4], bfr[4];
        #pragma unroll
        for (int i = 0; i < 4; ++i)
            af[i] = *(const bf16x8*)&As[wm * 64 + i * 16 + r16][quad * 8];
        #pragma unroll
        for (int j = 0; j < 4; ++j)
            bfr[j] = *(const bf16x8*)&Bs[wn * 64 + j * 16 + r16][quad * 8];
        #pragma unroll
        for (int i = 0; i < 4; ++i)
            #pragma unroll
            for (int j = 0; j < 4; ++j)
                acc[i][j] = __builtin_amdgcn_mfma_f32_16x16x32_bf16(af[i], bfr[j], acc[i][j], 0, 0, 0);
        __syncthreads();
    }

    #pragma unroll
    for (int j = 0; j < 4; ++j) {
        int ocol = tn * BN + wn * 64 + j * 16 + r16;
        float bv = bias[ocol];
        #pragma unroll
        for (int i = 0; i < 4; ++i) {
            int orow = tm * BM + wm * 64 + i * 16 + quad * 4;
            #pragma unroll
            for (int r = 0; r < 4; ++r) {
                float v = acc[i][j][r] + bv;
                if (mode == 1 && v < 0.0f) v = 0.0f;
                outb[(size_t)(orow + r) * N + ocol] = f2b(v);
            }
        }
    }
}

// ---- tiled GEMM, A rows gathered indirectly (FC1 + agent gather fused) ----
__global__ __launch_bounds__(256) void gemm_tiled_gather_k(const unsigned short* __restrict__ h_node,
                                                           const int* __restrict__ agent,
                                                           const int* __restrict__ nid,
                                                           const unsigned short* __restrict__ Bt,
                                                           const float* __restrict__ bias,
                                                           unsigned short* __restrict__ outb,
                                                           int M, int N, int K) {
    __shared__ unsigned short As[BM][LDK];
    __shared__ unsigned short Bs[BN][LDK];

    int tn = blockIdx.x;
    int tm = blockIdx.y;
    int tid = threadIdx.x;
    int lane = tid & 63;
    int wave = tid >> 6;
    int wm = wave >> 1, wn = wave & 1;
    int r16 = lane & 15, quad = lane >> 4;

    int srow = tid >> 2;
    int scol = (tid & 3) * 8;
    int c0 = nid[agent[tm * BM + srow]];
    int c1 = nid[agent[tm * BM + srow + 64]];
    const unsigned short* pa0 = h_node + (size_t)c0 * K + scol;
    const unsigned short* pa1 = h_node + (size_t)c1 * K + scol;
    const unsigned short* pb0 = Bt + (size_t)(tn * BN + srow) * K + scol;
    const unsigned short* pb1 = Bt + (size_t)(tn * BN + srow + 64) * K + scol;

    floatx4 acc[4][4];
    #pragma unroll
    for (int i = 0; i < 4; ++i)
        #pragma unroll
        for (int j = 0; j < 4; ++j)
            acc[i][j] = (floatx4){0.0f, 0.0f, 0.0f, 0.0f};

    bf16x8 ra0 = *(const bf16x8*)pa0;
    bf16x8 ra1 = *(const bf16x8*)pa1;
    bf16x8 rb0 = *(const bf16x8*)pb0;
    bf16x8 rb1 = *(const bf16x8*)pb1;

    for (int k0 = 0; k0 < K; k0 += BK) {
        *(bf16x8*)&As[srow][scol]      = ra0;
        *(bf16x8*)&As[srow + 64][scol] = ra1;
        *(bf16x8*)&Bs[srow][scol]      = rb0;
        *(bf16x8*)&Bs[srow + 64][scol] = rb1;
        __syncthreads();

        if (k0 + BK < K) {
            ra0 = *(const bf16x8*)(pa0 + k0 + BK);
            ra1 = *(const bf16x8*)(pa1 + k0 + BK);
            rb0 = *(const bf16x8*)(pb0 + k0 + BK);
            rb1 = *(const bf16x8*)(pb1 + k0 + BK);
        }

        bf16x8 af[4], bfr[4];
        #pragma unroll
        for (int i = 0; i < 4; ++i)
            af[i] = *(const bf16x8*)&As[wm * 64 + i * 16 + r16][quad * 8];
        #pragma unroll
        for (int j = 0; j < 4; ++j)
            bfr[j] = *(const bf16x8*)&Bs[wn * 64 + j * 16 + r16][quad * 8];
        #pragma unroll
        for (int i = 0; i < 4; ++i)
            #pragma unroll
            for (int j = 0; j < 4; ++j)
                acc[i][j] = __builtin_amdgcn_mfma_f32_16x16x32_bf16(af[i], bfr[j], acc[i][j], 0, 0, 0);
        __syncthreads();
    }

    #pragma unroll
    for (int j = 0; j < 4; ++j) {
        int ocol = tn * BN + wn * 64 + j * 16 + r16;
        float bv = bias[ocol];
        #pragma unroll
        for (int i = 0; i < 4; ++i) {
            int orow = tm * BM + wm * 64 + i * 16 + quad * 4;
            #pragma unroll
            for (int r = 0; r < 4; ++r)
                outb[(size_t)(orow + r) * N + ocol] = f2b(acc[i][j][r] + bv);
        }
    }
}

// ---- single-pass row LayerNorm (+affine) + relu, bf16 in -> bf16 out (FC1) ----
__global__ __launch_bounds__(256) void ln_relu_k(const unsigned short* __restrict__ z,
                                                 const float* __restrict__ g,
                                                 const float* __restrict__ be,
                                                 unsigned short* __restrict__ out, int L) {
    size_t base = (size_t)blockIdx.x * L;
    int nc = L >> 8;
    float vreg[4];
    float s = 0.0f, s2 = 0.0f;
    for (int i = 0; i < nc; ++i) {
        float v = b2f(z[base + i * 256 + threadIdx.x]);
        vreg[i] = v;
        s += v;
        s2 += v * v;
    }
    for (int off = 32; off > 0; off >>= 1) {
        s += __shfl_down(s, off);
        s2 += __shfl_down(s2, off);
    }
    __shared__ float red[8];
    int wave = threadIdx.x >> 6;
    int lane = threadIdx.x & 63;
    if (lane == 0) { red[wave] = s; red[4 + wave] = s2; }
    __syncthreads();
    s  = red[0] + red[1] + red[2] + red[3];
    s2 = red[4] + red[5] + red[6] + red[7];
    float invL = 1.0f / (float)L;
    float mean = s * invL;
    float var = s2 * invL - mean * mean;
    float inv = rsqrtf(var + 1e-5f);
    for (int i = 0; i < nc; ++i) {
        int c = i * 256 + threadIdx.x;
        float v = (vreg[i] - mean) * inv * g[c] + be[c];
        if (v < 0.0f) v = 0.0f;
        out[base + c] = f2b(v);
    }
}

// ---- fused LN2 + ReLU + head, 16 rows/block (512 blocks) ----
__global__ __launch_bounds__(256) void ln2head_k(const unsigned short* __restrict__ z,
                                                 const float* __restrict__ g2,
                                                 const float* __restrict__ be2,
                                                 const unsigned short* __restrict__ wmu_t,
                                                 const float* __restrict__ bmu,
                                                 float* __restrict__ out) {
    __shared__ unsigned short Hs[16][520];
    __shared__ float hred[4][64][4];
    int tid = threadIdx.x;
    int tm = blockIdx.x;
    {
        int row = tid >> 4;
        int sub = tid & 15;
        const unsigned short* src = z + (size_t)(tm * 16 + row) * FC2 + sub * 32;
        bf16x8 a0 = *(const bf16x8*)(src);
        bf16x8 a1 = *(const bf16x8*)(src + 8);
        bf16x8 a2 = *(const bf16x8*)(src + 16);
        bf16x8 a3 = *(const bf16x8*)(src + 24);
        float v[32];
        #pragma unroll
        for (int i = 0; i < 8; ++i) {
            v[i]      = b2f((unsigned short)a0[i]);
            v[8 + i]  = b2f((unsigned short)a1[i]);
            v[16 + i] = b2f((unsigned short)a2[i]);
            v[24 + i] = b2f((unsigned short)a3[i]);
        }
        float s = 0.0f, s2 = 0.0f;
        #pragma unroll
        for (int i = 0; i < 32; ++i) { s += v[i]; s2 += v[i] * v[i]; }
        #pragma unroll
        for (int m = 1; m < 16; m <<= 1) {
            s  += __shfl_xor(s, m);
            s2 += __shfl_xor(s2, m);
        }
        float mean = s * (1.0f / FC2);
        float var = s2 * (1.0f / FC2) - mean * mean;
        float inv = rsqrtf(var + 1e-5f);
        #pragma unroll
        for (int i = 0; i < 32; ++i) {
            int c = sub * 32 + i;
            float w = (v[i] - mean) * inv * g2[c] + be2[c];
            if (w < 0.0f) w = 0.0f;
            Hs[row][c] = f2b(w);
        }
    }
    __syncthreads();
    int lane = tid & 63, wave = tid >> 6;
    int r16 = lane & 15, quad = lane >> 4;
    floatx4 acc = {0.0f, 0.0f, 0.0f, 0.0f};
    #pragma unroll
    for (int st = 0; st < 4; ++st) {
        bf16x8 a = *(const bf16x8*)&Hs[r16][wave * 128 + st * 32 + quad * 8];
        bf16x8 b = *(const bf16x8*)(wmu_t + (size_t)r16 * FC2 + wave * 128 + st * 32 + quad * 8);
        acc = __builtin_amdgcn_mfma_f32_16x16x32_bf16(a, b, acc, 0, 0, 0);
    }
    #pragma unroll
    for (int r = 0; r < 4; ++r) hred[wave][lane][r] = acc[r];
    __syncthreads();
    if (wave == 0) {
        #pragma unroll
        for (int r = 0; r < 4; ++r) {
            float v = hred[0][lane][r] + hred[1][lane][r] + hred[2][lane][r] + hred[3][lane][r];
            v += bmu[r16];
            v = 1.0f / (1.0f + expf(-v));
            out[(size_t)(tm * 16 + quad * 4 + r) * N_ACT + r16] = v;
        }
    }
}

extern "C" void kernel_launch(void* const* d_in, const int* in_sizes, int n_in,
                              void* d_out, int out_size, void* d_ws, size_t ws_size,
                              hipStream_t stream) {
    const float* x    = (const float*)d_in[0];
    const int*   ei   = (const int*)d_in[1];
    const int*   agent= (const int*)d_in[2];
    const float* Wgcn = (const float*)d_in[3];
    const float* bgcn = (const float*)d_in[4];
    const float* W1   = (const float*)d_in[5];
    const float* b1   = (const float*)d_in[6];
    const float* g1   = (const float*)d_in[7];
    const float* be1  = (const float*)d_in[8];
    const float* W2   = (const float*)d_in[9];
    const float* b2   = (const float*)d_in[10];
    const float* g2   = (const float*)d_in[11];
    const float* be2  = (const float*)d_in[12];
    const float* Wmu  = (const float*)d_in[13];
    const float* bmu  = (const float*)d_in[14];
    float* out = (float*)d_out;

    const int* srcp = ei;
    const int* dstp = ei + N_EDGES;

    // workspace layout (256B aligned). Zero-init region contiguous: deg|fill|cnt|etot.
    char* ws = (char*)d_ws;
    size_t off = 0;
    char* zero_base = ws;
    int* deg = (int*)(ws + off);     off += ((size_t)N_NODES * 4 + 255) & ~(size_t)255;
    int* fill = (int*)(ws + off);    off += ((size_t)N_AGENTS * 4 + 255) & ~(size_t)255;
    int* cnt = (int*)(ws + off);     off += 256;
    int* etot = (int*)(ws + off);    off += 256;
    size_t zero_bytes = off;
    int* nid = (int*)(ws + off);     off += ((size_t)N_NODES * 4 + 255) & ~(size_t)255;
    float* dis = (float*)(ws + off); off += ((size_t)N_NODES * 4 + 255) & ~(size_t)255;
    int* list = (int*)(ws + off);    off += ((size_t)N_AGENTS * 4 + 255) & ~(size_t)255;
    int* rowbeg = (int*)(ws + off);  off += ((size_t)N_AGENTS * 4 + 255) & ~(size_t)255;
    int* ebuf = (int*)(ws + off);    off += ((size_t)N_EDGES * 4 + 255) & ~(size_t)255;
    unsigned short* wgcn_t = (unsigned short*)(ws + off); off += ((size_t)IN_DIM * HID * 2 + 255) & ~(size_t)255;
    unsigned short* w1_t   = (unsigned short*)(ws + off); off += ((size_t)HID * FC1 * 2 + 255) & ~(size_t)255;
    unsigned short* w2_t   = (unsigned short*)(ws + off); off += ((size_t)FC1 * FC2 * 2 + 255) & ~(size_t)255;
    unsigned short* wmu_t  = (unsigned short*)(ws + off); off += ((size_t)FC2 * N_ACT * 2 + 255) & ~(size_t)255;
    unsigned short* agg    = (unsigned short*)(ws + off); off += ((size_t)N_AGENTS * IN_DIM * 2 + 255) & ~(size_t)255;
    unsigned short* h_node = (unsigned short*)(ws + off); off += ((size_t)N_AGENTS * HID * 2 + 255) & ~(size_t)255;
    unsigned short* zb = (unsigned short*)(ws + off);     off += ((size_t)N_AGENTS * FC1 * 2 + 255) & ~(size_t)255;
    unsigned short* h1 = (unsigned short*)(ws + off);     off += ((size_t)N_AGENTS * FC1 * 2 + 255) & ~(size_t)255;

    // ---- init via memset: zeros + nid=-1 ----
    hipMemsetAsync(zero_base, 0, zero_bytes, stream);
    hipMemsetAsync(nid, 0xFF, (size_t)N_NODES * 4, stream);

    // ---- graph prep / CSR build ----
    prep1_k<<<(N_EDGES + 255) / 256, 256, 0, stream>>>(agent, nid, dstp, deg);
    prep2_k<<<(N_NODES + 255) / 256, 256, 0, stream>>>(nid, list, cnt, deg, rowbeg, etot, dis);
    fill_k<<<(N_EDGES + 255) / 256, 256, 0, stream>>>(srcp, dstp, nid, rowbeg, fill, ebuf);

    // ---- weight transpose+convert ----
    wtr_k<<<208, 256, 0, stream>>>(Wgcn, W1, W2, Wmu, wgcn_t, w1_t, w2_t, wmu_t);

    // ---- aggregate raw x per needed node (GCN aggregation first) ----
    accumx_k<<<N_AGENTS, 256, 0, stream>>>(cnt, list, rowbeg, deg, ebuf, dis, x, agg);

    // ---- GCN layer on compact rows: h_node = relu(agg @ Wgcn + bgcn) ----
    {
        dim3 grid(HID / BN, N_AGENTS / BM);          // 2 x 64
        gemm_tiled_k<<<grid, 256, 0, stream>>>(agg, wgcn_t, bgcn, h_node,
                                               N_AGENTS, HID, IN_DIM, 1);
    }

    // FC1 (agent gather fused) -> LN+relu
    {
        dim3 grid(FC1 / BN, N_AGENTS / BM);
        gemm_tiled_gather_k<<<grid, 256, 0, stream>>>(h_node, agent, nid, w1_t, b1, zb,
                                                      N_AGENTS, FC1, HID);
        ln_relu_k<<<N_AGENTS, 256, 0, stream>>>(zb, g1, be1, h1, FC1);
    }

    // FC2 -> fused LN + head (16 rows/block)
    {
        dim3 grid(FC2 / BN, N_AGENTS / BM);
        gemm_tiled_k<<<grid, 256, 0, stream>>>(h1, w2_t, b2, zb, N_AGENTS, FC2, FC1, 0);
        ln2head_k<<<N_AGENTS / 16, 256, 0, stream>>>(zb, g2, be2, wmu_t, bmu, out);
    }
}

// Round 13
// 233.715 us; speedup vs baseline: 1.2337x; 1.0268x over previous
//
#include <hip/hip_runtime.h>
#include <hip/hip_bf16.h>
#include <math.h>

#define N_NODES  50000
#define N_EDGES  800000
#define IN_DIM   128
#define HID      256
#define FC1      1024
#define FC2      512
#define N_ACT    16
#define N_AGENTS 8192

#define BM 128
#define BN 128
#define BK 32
#define LDK 40   // padded LDS leading dim for tiled GEMMs

#define PREP1_BLOCKS ((N_EDGES + 255) / 256)    // 3125
#define WTR_BLOCKS   208

typedef short bf16x8 __attribute__((ext_vector_type(8)));
typedef float floatx4 __attribute__((ext_vector_type(4)));

__device__ __forceinline__ unsigned short f2b(float f) {
    union { float f; unsigned int i; } v;
    v.f = f;
    unsigned int lsb = (v.i >> 16) & 1u;
    v.i += 0x7fffu + lsb;            // round-to-nearest-even
    return (unsigned short)(v.i >> 16);
}

__device__ __forceinline__ float b2f(unsigned short u) {
    union { unsigned int i; float f; } v;
    v.i = ((unsigned int)u) << 16;
    return v.f;
}

// ---- fused: (blocks 0..3124) claim + degree; (blocks 3125..3332) weight transpose ----
__global__ __launch_bounds__(256) void prep1w_k(const int* __restrict__ agent_idx,
                                                int* __restrict__ nid,
                                                const int* __restrict__ dst,
                                                int* __restrict__ deg,
                                                const float* __restrict__ Wgcn,
                                                const float* __restrict__ W1,
                                                const float* __restrict__ W2,
                                                const float* __restrict__ Wmu,
                                                unsigned short* __restrict__ wgcn_t,
                                                unsigned short* __restrict__ w1_t,
                                                unsigned short* __restrict__ w2_t,
                                                unsigned short* __restrict__ wmu_t) {
    __shared__ unsigned short Ts[64][72];
    if (blockIdx.x < PREP1_BLOCKS) {
        int i = blockIdx.x * 256 + threadIdx.x;
        if (i < N_AGENTS) atomicCAS(&nid[agent_idx[i]], -1, i);
        if (i < N_EDGES) atomicAdd(&deg[dst[i]], 1);
        return;
    }
    int b = blockIdx.x - PREP1_BLOCKS;
    const float* src; unsigned short* dstp; int K, N, tk, tn;
    if (b < 8)        { src = Wgcn; dstp = wgcn_t; K = IN_DIM; N = HID;  tk = b >> 2;        tn = b & 3; }
    else if (b < 72)  { int bb = b - 8;  src = W1; dstp = w1_t; K = HID;  N = FC1;  tk = bb >> 4; tn = bb & 15; }
    else if (b < 200) { int bb = b - 72; src = W2; dstp = w2_t; K = FC1;  N = FC2;  tk = bb >> 3; tn = bb & 7; }
    else              { int bb = b - 200; src = Wmu; dstp = wmu_t; K = FC2; N = N_ACT; tk = bb;   tn = 0; }
    int k0 = tk * 64, n0 = tn * 64;
    int tid = threadIdx.x;
    int r  = tid >> 2;
    int cc = (tid & 3) * 16;
    if (n0 + cc < N) {
        const float* p = src + (size_t)(k0 + r) * N + n0 + cc;
        #pragma unroll
        for (int i = 0; i < 16; i += 4) {
            float4 v = *(const float4*)(p + i);
            Ts[r][cc + i + 0] = f2b(v.x);
            Ts[r][cc + i + 1] = f2b(v.y);
            Ts[r][cc + i + 2] = f2b(v.z);
            Ts[r][cc + i + 3] = f2b(v.w);
        }
    }
    __syncthreads();
    int n = tid >> 2;
    if (n0 + n < N) {
        bf16x8 o0, o1;
        #pragma unroll
        for (int i = 0; i < 8; ++i) o0[i] = (short)Ts[cc + i][n];
        #pragma unroll
        for (int i = 0; i < 8; ++i) o1[i] = (short)Ts[cc + 8 + i][n];
        unsigned short* q = dstp + (size_t)(n0 + n) * K + k0 + cc;
        *(bf16x8*)q = o0;
        *(bf16x8*)(q + 8) = o1;
    }
}

// ---- fused: compact ids + bump-alloc row bases + dis = rsqrt(deg+1) ----
__global__ __launch_bounds__(256) void prep2_k(int* __restrict__ nid,
                                               int* __restrict__ list,
                                               int* __restrict__ cnt,
                                               const int* __restrict__ deg,
                                               int* __restrict__ rowbeg,
                                               int* __restrict__ etot,
                                               float* __restrict__ dis) {
    int i = blockIdx.x * 256 + threadIdx.x;
    if (i < N_NODES) {
        int d = deg[i];
        dis[i] = rsqrtf((float)(d + 1));
        if (nid[i] != -1) {
            int c = atomicAdd(cnt, 1);
            nid[i] = c;
            list[c] = i;
            rowbeg[c] = atomicAdd(etot, d);
        }
    }
}

// ---- fill buckets: for needed dsts, append src to its row ----
__global__ __launch_bounds__(256) void fill_k(const int* __restrict__ src,
                                              const int* __restrict__ dst,
                                              const int* __restrict__ nid,
                                              const int* __restrict__ rowbeg,
                                              int* __restrict__ fill,
                                              int* __restrict__ ebuf) {
    int e = blockIdx.x * 256 + threadIdx.x;
    if (e >= N_EDGES) return;
    int c = nid[dst[e]];
    if (c < 0) return;
    int p = atomicAdd(&fill[c], 1);
    ebuf[rowbeg[c] + p] = src[e];
}

// ---- aggregate raw x rows per needed node (GCN aggregation before the GEMM) ----
__global__ __launch_bounds__(256) void accumx_k(const int* __restrict__ cntp,
                                                const int* __restrict__ list,
                                                const int* __restrict__ rowbeg,
                                                const int* __restrict__ deg,
                                                const int* __restrict__ ebuf,
                                                const float* __restrict__ dis,
                                                const float* __restrict__ x,
                                                unsigned short* __restrict__ agg) {
    int c = blockIdx.x;
    if (c >= *cntp) return;
    int n = list[c];
    int lane = threadIdx.x & 63;
    int wave = threadIdx.x >> 6;
    int beg = rowbeg[c];
    int end = beg + deg[n];
    float dn = dis[n];
    float ax = 0.0f, ay = 0.0f;
    for (int i = beg + wave; i < end; i += 4) {
        int s = ebuf[i];
        float w = dis[s] * dn;
        float2 u = *(const float2*)(x + (size_t)s * IN_DIM + lane * 2);
        ax += w * u.x;
        ay += w * u.y;
    }
    __shared__ float part[4][IN_DIM];
    part[wave][lane * 2 + 0] = ax;
    part[wave][lane * 2 + 1] = ay;
    __syncthreads();
    int t = threadIdx.x;
    if (t < IN_DIM) {
        float v = part[0][t] + part[1][t] + part[2][t] + part[3][t];
        v += dn * dn * x[(size_t)n * IN_DIM + t];
        agg[(size_t)c * IN_DIM + t] = f2b(v);
    }
}

// ---- tiled GEMM, BM=64 x BN=128 (higher block count for small GEMMs) ----
// mode 0: bf16(v + bias);  mode 1: bf16(relu(v + bias))
__global__ __launch_bounds__(256) void gemm_tiled64_k(const unsigned short* __restrict__ A,
                                                      const unsigned short* __restrict__ Bt,
                                                      const float* __restrict__ bias,
                                                      unsigned short* __restrict__ outb,
                                                      int M, int N, int K, int mode) {
    __shared__ unsigned short As[64][LDK];
    __shared__ unsigned short Bs[128][LDK];

    int tn = blockIdx.x;
    int tm = blockIdx.y;
    int tid = threadIdx.x;
    int lane = tid & 63;
    int wave = tid >> 6;          // wave covers cols [wave*32, wave*32+32)
    int r16 = lane & 15, quad = lane >> 4;

    int srow = tid >> 2;          // 0..63
    int scol = (tid & 3) * 8;
    const unsigned short* pa0 = A + (size_t)(tm * 64 + srow) * K + scol;
    const unsigned short* pb0 = Bt + (size_t)(tn * 128 + srow) * K + scol;
    const unsigned short* pb1 = Bt + (size_t)(tn * 128 + srow + 64) * K + scol;

    floatx4 acc[4][2];
    #pragma unroll
    for (int i = 0; i < 4; ++i)
        #pragma unroll
        for (int j = 0; j < 2; ++j)
            acc[i][j] = (floatx4){0.0f, 0.0f, 0.0f, 0.0f};

    bf16x8 ra0 = *(const bf16x8*)pa0;
    bf16x8 rb0 = *(const bf16x8*)pb0;
    bf16x8 rb1 = *(const bf16x8*)pb1;

    for (int k0 = 0; k0 < K; k0 += BK) {
        *(bf16x8*)&As[srow][scol]      = ra0;
        *(bf16x8*)&Bs[srow][scol]      = rb0;
        *(bf16x8*)&Bs[srow + 64][scol] = rb1;
        __syncthreads();

        if (k0 + BK < K) {
            ra0 = *(const bf16x8*)(pa0 + k0 + BK);
            rb0 = *(const bf16x8*)(pb0 + k0 + BK);
            rb1 = *(const bf16x8*)(pb1 + k0 + BK);
        }

        bf16x8 af[4], bfr[2];
        #pragma unroll
        for (int i = 0; i < 4; ++i)
            af[i] = *(const bf16x8*)&As[i * 16 + r16][quad * 8];
        #pragma unroll
        for (int j = 0; j < 2; ++j)
            bfr[j] = *(const bf16x8*)&Bs[wave * 32 + j * 16 + r16][quad * 8];
        #pragma unroll
        for (int i = 0; i < 4; ++i)
            #pragma unroll
            for (int j = 0; j < 2; ++j)
                acc[i][j] = __builtin_amdgcn_mfma_f32_16x16x32_bf16(af[i], bfr[j], acc[i][j], 0, 0, 0);
        __syncthreads();
    }

    #pragma unroll
    for (int j = 0; j < 2; ++j) {
        int ocol = tn * 128 + wave * 32 + j * 16 + r16;
        float bv = bias[ocol];
        #pragma unroll
        for (int i = 0; i < 4; ++i) {
            int orow = tm * 64 + i * 16 + quad * 4;
            #pragma unroll
            for (int r = 0; r < 4; ++r) {
                float v = acc[i][j][r] + bv;
                if (mode == 1 && v < 0.0f) v = 0.0f;
                outb[(size_t)(orow + r) * N + ocol] = f2b(v);
            }
        }
    }
}

// ---- tiled GEMM 128x128, A rows gathered indirectly (FC1 + agent gather fused) ----
__global__ __launch_bounds__(256) void gemm_tiled_gather_k(const unsigned short* __restrict__ h_node,
                                                           const int* __restrict__ agent,
                                                           const int* __restrict__ nid,
                                                           const unsigned short* __restrict__ Bt,
                                                           const float* __restrict__ bias,
                                                           unsigned short* __restrict__ outb,
                                                           int M, int N, int K) {
    __shared__ unsigned short As[BM][LDK];
    __shared__ unsigned short Bs[BN][LDK];

    int tn = blockIdx.x;
    int tm = blockIdx.y;
    int tid = threadIdx.x;
    int lane = tid & 63;
    int wave = tid >> 6;
    int wm = wave >> 1, wn = wave & 1;
    int r16 = lane & 15, quad = lane >> 4;

    int srow = tid >> 2;
    int scol = (tid & 3) * 8;
    int c0 = nid[agent[tm * BM + srow]];
    int c1 = nid[agent[tm * BM + srow + 64]];
    const unsigned short* pa0 = h_node + (size_t)c0 * K + scol;
    const unsigned short* pa1 = h_node + (size_t)c1 * K + scol;
    const unsigned short* pb0 = Bt + (size_t)(tn * BN + srow) * K + scol;
    const unsigned short* pb1 = Bt + (size_t)(tn * BN + srow + 64) * K + scol;

    floatx4 acc[4][4];
    #pragma unroll
    for (int i = 0; i < 4; ++i)
        #pragma unroll
        for (int j = 0; j < 4; ++j)
            acc[i][j] = (floatx4){0.0f, 0.0f, 0.0f, 0.0f};

    bf16x8 ra0 = *(const bf16x8*)pa0;
    bf16x8 ra1 = *(const bf16x8*)pa1;
    bf16x8 rb0 = *(const bf16x8*)pb0;
    bf16x8 rb1 = *(const bf16x8*)pb1;

    for (int k0 = 0; k0 < K; k0 += BK) {
        *(bf16x8*)&As[srow][scol]      = ra0;
        *(bf16x8*)&As[srow + 64][scol] = ra1;
        *(bf16x8*)&Bs[srow][scol]      = rb0;
        *(bf16x8*)&Bs[srow + 64][scol] = rb1;
        __syncthreads();

        if (k0 + BK < K) {
            ra0 = *(const bf16x8*)(pa0 + k0 + BK);
            ra1 = *(const bf16x8*)(pa1 + k0 + BK);
            rb0 = *(const bf16x8*)(pb0 + k0 + BK);
            rb1 = *(const bf16x8*)(pb1 + k0 + BK);
        }

        bf16x8 af[4], bfr[4];
        #pragma unroll
        for (int i = 0; i < 4; ++i)
            af[i] = *(const bf16x8*)&As[wm * 64 + i * 16 + r16][quad * 8];
        #pragma unroll
        for (int j = 0; j < 4; ++j)
            bfr[j] = *(const bf16x8*)&Bs[wn * 64 + j * 16 + r16][quad * 8];
        #pragma unroll
        for (int i = 0; i < 4; ++i)
            #pragma unroll
            for (int j = 0; j < 4; ++j)
                acc[i][j] = __builtin_amdgcn_mfma_f32_16x16x32_bf16(af[i], bfr[j], acc[i][j], 0, 0, 0);
        __syncthreads();
    }

    #pragma unroll
    for (int j = 0; j < 4; ++j) {
        int ocol = tn * BN + wn * 64 + j * 16 + r16;
        float bv = bias[ocol];
        #pragma unroll
        for (int i = 0; i < 4; ++i) {
            int orow = tm * BM + wm * 64 + i * 16 + quad * 4;
            #pragma unroll
            for (int r = 0; r < 4; ++r)
                outb[(size_t)(orow + r) * N + ocol] = f2b(acc[i][j][r] + bv);
        }
    }
}

// ---- single-pass row LayerNorm (+affine) + relu, bf16 in -> bf16 out (FC1) ----
__global__ __launch_bounds__(256) void ln_relu_k(const unsigned short* __restrict__ z,
                                                 const float* __restrict__ g,
                                                 const float* __restrict__ be,
                                                 unsigned short* __restrict__ out, int L) {
    size_t base = (size_t)blockIdx.x * L;
    int nc = L >> 8;
    float vreg[4];
    float s = 0.0f, s2 = 0.0f;
    for (int i = 0; i < nc; ++i) {
        float v = b2f(z[base + i * 256 + threadIdx.x]);
        vreg[i] = v;
        s += v;
        s2 += v * v;
    }
    for (int off = 32; off > 0; off >>= 1) {
        s += __shfl_down(s, off);
        s2 += __shfl_down(s2, off);
    }
    __shared__ float red[8];
    int wave = threadIdx.x >> 6;
    int lane = threadIdx.x & 63;
    if (lane == 0) { red[wave] = s; red[4 + wave] = s2; }
    __syncthreads();
    s  = red[0] + red[1] + red[2] + red[3];
    s2 = red[4] + red[5] + red[6] + red[7];
    float invL = 1.0f / (float)L;
    float mean = s * invL;
    float var = s2 * invL - mean * mean;
    float inv = rsqrtf(var + 1e-5f);
    for (int i = 0; i < nc; ++i) {
        int c = i * 256 + threadIdx.x;
        float v = (vreg[i] - mean) * inv * g[c] + be[c];
        if (v < 0.0f) v = 0.0f;
        out[base + c] = f2b(v);
    }
}

// ---- fused LN2 + ReLU + head, 16 rows/block (512 blocks) ----
__global__ __launch_bounds__(256) void ln2head_k(const unsigned short* __restrict__ z,
                                                 const float* __restrict__ g2,
                                                 const float* __restrict__ be2,
                                                 const unsigned short* __restrict__ wmu_t,
                                                 const float* __restrict__ bmu,
                                                 float* __restrict__ out) {
    __shared__ unsigned short Hs[16][520];
    __shared__ float hred[4][64][4];
    int tid = threadIdx.x;
    int tm = blockIdx.x;
    {
        int row = tid >> 4;
        int sub = tid & 15;
        const unsigned short* src = z + (size_t)(tm * 16 + row) * FC2 + sub * 32;
        bf16x8 a0 = *(const bf16x8*)(src);
        bf16x8 a1 = *(const bf16x8*)(src + 8);
        bf16x8 a2 = *(const bf16x8*)(src + 16);
        bf16x8 a3 = *(const bf16x8*)(src + 24);
        float v[32];
        #pragma unroll
        for (int i = 0; i < 8; ++i) {
            v[i]      = b2f((unsigned short)a0[i]);
            v[8 + i]  = b2f((unsigned short)a1[i]);
            v[16 + i] = b2f((unsigned short)a2[i]);
            v[24 + i] = b2f((unsigned short)a3[i]);
        }
        float s = 0.0f, s2 = 0.0f;
        #pragma unroll
        for (int i = 0; i < 32; ++i) { s += v[i]; s2 += v[i] * v[i]; }
        #pragma unroll
        for (int m = 1; m < 16; m <<= 1) {
            s  += __shfl_xor(s, m);
            s2 += __shfl_xor(s2, m);
        }
        float mean = s * (1.0f / FC2);
        float var = s2 * (1.0f / FC2) - mean * mean;
        float inv = rsqrtf(var + 1e-5f);
        #pragma unroll
        for (int i = 0; i < 32; ++i) {
            int c = sub * 32 + i;
            float w = (v[i] - mean) * inv * g2[c] + be2[c];
            if (w < 0.0f) w = 0.0f;
            Hs[row][c] = f2b(w);
        }
    }
    __syncthreads();
    int lane = tid & 63, wave = tid >> 6;
    int r16 = lane & 15, quad = lane >> 4;
    floatx4 acc = {0.0f, 0.0f, 0.0f, 0.0f};
    #pragma unroll
    for (int st = 0; st < 4; ++st) {
        bf16x8 a = *(const bf16x8*)&Hs[r16][wave * 128 + st * 32 + quad * 8];
        bf16x8 b = *(const bf16x8*)(wmu_t + (size_t)r16 * FC2 + wave * 128 + st * 32 + quad * 8);
        acc = __builtin_amdgcn_mfma_f32_16x16x32_bf16(a, b, acc, 0, 0, 0);
    }
    #pragma unroll
    for (int r = 0; r < 4; ++r) hred[wave][lane][r] = acc[r];
    __syncthreads();
    if (wave == 0) {
        #pragma unroll
        for (int r = 0; r < 4; ++r) {
            float v = hred[0][lane][r] + hred[1][lane][r] + hred[2][lane][r] + hred[3][lane][r];
            v += bmu[r16];
            v = 1.0f / (1.0f + expf(-v));
            out[(size_t)(tm * 16 + quad * 4 + r) * N_ACT + r16] = v;
        }
    }
}

extern "C" void kernel_launch(void* const* d_in, const int* in_sizes, int n_in,
                              void* d_out, int out_size, void* d_ws, size_t ws_size,
                              hipStream_t stream) {
    const float* x    = (const float*)d_in[0];
    const int*   ei   = (const int*)d_in[1];
    const int*   agent= (const int*)d_in[2];
    const float* Wgcn = (const float*)d_in[3];
    const float* bgcn = (const float*)d_in[4];
    const float* W1   = (const float*)d_in[5];
    const float* b1   = (const float*)d_in[6];
    const float* g1   = (const float*)d_in[7];
    const float* be1  = (const float*)d_in[8];
    const float* W2   = (const float*)d_in[9];
    const float* b2   = (const float*)d_in[10];
    const float* g2   = (const float*)d_in[11];
    const float* be2  = (const float*)d_in[12];
    const float* Wmu  = (const float*)d_in[13];
    const float* bmu  = (const float*)d_in[14];
    float* out = (float*)d_out;

    const int* srcp = ei;
    const int* dstp = ei + N_EDGES;

    // workspace layout (256B aligned). Zero-init region contiguous: deg|fill|cnt|etot.
    char* ws = (char*)d_ws;
    size_t off = 0;
    char* zero_base = ws;
    int* deg = (int*)(ws + off);     off += ((size_t)N_NODES * 4 + 255) & ~(size_t)255;
    int* fill = (int*)(ws + off);    off += ((size_t)N_AGENTS * 4 + 255) & ~(size_t)255;
    int* cnt = (int*)(ws + off);     off += 256;
    int* etot = (int*)(ws + off);    off += 256;
    size_t zero_bytes = off;
    int* nid = (int*)(ws + off);     off += ((size_t)N_NODES * 4 + 255) & ~(size_t)255;
    float* dis = (float*)(ws + off); off += ((size_t)N_NODES * 4 + 255) & ~(size_t)255;
    int* list = (int*)(ws + off);    off += ((size_t)N_AGENTS * 4 + 255) & ~(size_t)255;
    int* rowbeg = (int*)(ws + off);  off += ((size_t)N_AGENTS * 4 + 255) & ~(size_t)255;
    int* ebuf = (int*)(ws + off);    off += ((size_t)N_EDGES * 4 + 255) & ~(size_t)255;
    unsigned short* wgcn_t = (unsigned short*)(ws + off); off += ((size_t)IN_DIM * HID * 2 + 255) & ~(size_t)255;
    unsigned short* w1_t   = (unsigned short*)(ws + off); off += ((size_t)HID * FC1 * 2 + 255) & ~(size_t)255;
    unsigned short* w2_t   = (unsigned short*)(ws + off); off += ((size_t)FC1 * FC2 * 2 + 255) & ~(size_t)255;
    unsigned short* wmu_t  = (unsigned short*)(ws + off); off += ((size_t)FC2 * N_ACT * 2 + 255) & ~(size_t)255;
    unsigned short* agg    = (unsigned short*)(ws + off); off += ((size_t)N_AGENTS * IN_DIM * 2 + 255) & ~(size_t)255;
    unsigned short* h_node = (unsigned short*)(ws + off); off += ((size_t)N_AGENTS * HID * 2 + 255) & ~(size_t)255;
    unsigned short* zb = (unsigned short*)(ws + off);     off += ((size_t)N_AGENTS * FC1 * 2 + 255) & ~(size_t)255;
    unsigned short* h1 = (unsigned short*)(ws + off);     off += ((size_t)N_AGENTS * FC1 * 2 + 255) & ~(size_t)255;

    // ---- init via memset: zeros + nid=-1 ----
    hipMemsetAsync(zero_base, 0, zero_bytes, stream);
    hipMemsetAsync(nid, 0xFF, (size_t)N_NODES * 4, stream);

    // ---- fused: claim+degree (edge blocks) + weight transpose (tail blocks) ----
    prep1w_k<<<PREP1_BLOCKS + WTR_BLOCKS, 256, 0, stream>>>(agent, nid, dstp, deg,
                                                            Wgcn, W1, W2, Wmu,
                                                            wgcn_t, w1_t, w2_t, wmu_t);

    prep2_k<<<(N_NODES + 255) / 256, 256, 0, stream>>>(nid, list, cnt, deg, rowbeg, etot, dis);
    fill_k<<<(N_EDGES + 255) / 256, 256, 0, stream>>>(srcp, dstp, nid, rowbeg, fill, ebuf);

    // ---- aggregate raw x per needed node ----
    accumx_k<<<N_AGENTS, 256, 0, stream>>>(cnt, list, rowbeg, deg, ebuf, dis, x, agg);

    // ---- GCN layer: h_node = relu(agg @ Wgcn + bgcn)  (BM=64 tile, 256 blocks) ----
    {
        dim3 grid(HID / 128, N_AGENTS / 64);
        gemm_tiled64_k<<<grid, 256, 0, stream>>>(agg, wgcn_t, bgcn, h_node,
                                                 N_AGENTS, HID, IN_DIM, 1);
    }

    // FC1 (agent gather fused) -> LN+relu
    {
        dim3 grid(FC1 / BN, N_AGENTS / BM);
        gemm_tiled_gather_k<<<grid, 256, 0, stream>>>(h_node, agent, nid, w1_t, b1, zb,
                                                      N_AGENTS, FC1, HID);
        ln_relu_k<<<N_AGENTS, 256, 0, stream>>>(zb, g1, be1, h1, FC1);
    }

    // FC2 (BM=64 tile, 512 blocks) -> fused LN + head
    {
        dim3 grid(FC2 / 128, N_AGENTS / 64);
        gemm_tiled64_k<<<grid, 256, 0, stream>>>(h1, w2_t, b2, zb, N_AGENTS, FC2, FC1, 0);
        ln2head_k<<<N_AGENTS / 16, 256, 0, stream>>>(zb, g2, be2, wmu_t, bmu, out);
    }
}